// Round 5
// baseline (483.763 us; speedup 1.0000x reference)
//
#include <hip/hip_runtime.h>
#include <hip/hip_bf16.h>
#include <cmath>

#define E_ 256
#define H_ 8
#define DH 32
#define MLPD 1024
#define LATD 128
#define TOPK_ 32
#define BB 2
#define RR 1024
#define CC 4
#define NT 8192      // B*R*C tokens
#define BF 8         // B*C
#define SPLIT 768

using bf16x8 = __attribute__((ext_vector_type(8))) short;
using f32x4v = __attribute__((ext_vector_type(4))) float;

__device__ __forceinline__ unsigned short f2b(float x) {
    __hip_bfloat16 h = __float2bfloat16(x);
    return *reinterpret_cast<unsigned short*>(&h);
}

// ---------------------------------------------------------------------------
// Fused f32 -> bf16 converter for weights + src (8 segments)
// ---------------------------------------------------------------------------
struct ConvArgs {
    const float* s[8];
    unsigned short* d[8];
    int cum[8];   // cumulative quad counts (exclusive prefix ends)
};
__global__ __launch_bounds__(256) void convert_f2b(ConvArgs a, int totq)
{
    int q = blockIdx.x * 256 + threadIdx.x;
    if (q >= totq) return;
    int seg = 0;
    while (q >= a.cum[seg]) seg++;
    int lq = q - (seg ? a.cum[seg - 1] : 0);
    float4 v = ((const float4*)a.s[seg])[lq];
    ushort4 o;
    o.x = f2b(v.x); o.y = f2b(v.y); o.z = f2b(v.z); o.w = f2b(v.w);
    ((ushort4*)a.d[seg])[lq] = o;
}

// ---------------------------------------------------------------------------
// bf16 MFMA GEMM: C[M][N] = A(MxK bf16) @ W(NxK bf16)^T (+bias)(+gelu)(+res f32)
// TMxTN tile, 4 waves (2x2), frags of 16x16x32.
// AMAP: A-row gather (train rows). OMAP: st-row -> BRCE token row scatter.
// OUTBF: write bf16 (Ch) instead of f32 (Cf).
// ---------------------------------------------------------------------------
template<int TM, int TN, int BIAS, int GELU, int RES, int AMAP, int OMAP, int OUTBF>
__global__ __launch_bounds__(256) void gemm_mfma(
    const unsigned short* __restrict__ A, const unsigned short* __restrict__ W,
    const float* __restrict__ bias, const float* __restrict__ res,
    float* __restrict__ Cf, unsigned short* __restrict__ Ch,
    int M, int N, int K)
{
    __shared__ __align__(16) unsigned short As[TM * 40];
    __shared__ __align__(16) unsigned short Bs[TN * 40];
    const int tid = threadIdx.x;
    const int lane = tid & 63, wave = tid >> 6;
    const int wr = wave >> 1, wc = wave & 1;
    const int m0 = blockIdx.y * TM, n0 = blockIdx.x * TN;

    // staging coordinates
    int ra, kqa;
    if constexpr (TM == 128) { ra = tid >> 1; kqa = (tid & 1) * 16; }
    else                     { ra = tid >> 2; kqa = (tid & 3) * 8; }
    int rb, kqb;
    if constexpr (TN == 128) { rb = tid >> 1; kqb = (tid & 1) * 16; }
    else                     { rb = tid >> 2; kqb = (tid & 3) * 8; }

    int am = m0 + ra;
    size_t arow = AMAP ? ((size_t)(am / SPLIT) * RR + (am % SPLIT)) : (size_t)am;
    const unsigned short* Ap = A + arow * (size_t)K + kqa;
    const unsigned short* Bp = W + (size_t)(n0 + rb) * K + kqb;

    constexpr int FM = TM / 32, FN = TN / 32;
    f32x4v acc[FM][FN];
#pragma unroll
    for (int i = 0; i < FM; i++)
#pragma unroll
        for (int j = 0; j < FN; j++) acc[i][j] = (f32x4v){0.f, 0.f, 0.f, 0.f};

    const int kof = (lane >> 4) * 8;
    int arow_lds[FM], brow_lds[FN];
#pragma unroll
    for (int f = 0; f < FM; f++)
        arow_lds[f] = (wr * (TM / 2) + f * 16 + (lane & 15)) * 40 + kof;
#pragma unroll
    for (int f = 0; f < FN; f++)
        brow_lds[f] = (wc * (TN / 2) + f * 16 + (lane & 15)) * 40 + kof;

    for (int k0 = 0; k0 < K; k0 += 32) {
        int4 va0, va1, vb0, vb1;
        va0 = *(const int4*)(Ap + k0);
        if constexpr (TM == 128) va1 = *(const int4*)(Ap + k0 + 8);
        vb0 = *(const int4*)(Bp + k0);
        if constexpr (TN == 128) vb1 = *(const int4*)(Bp + k0 + 8);
        __syncthreads();
        *(int4*)&As[ra * 40 + kqa] = va0;
        if constexpr (TM == 128) *(int4*)&As[ra * 40 + kqa + 8] = va1;
        *(int4*)&Bs[rb * 40 + kqb] = vb0;
        if constexpr (TN == 128) *(int4*)&Bs[rb * 40 + kqb + 8] = vb1;
        __syncthreads();
        bf16x8 af[FM], bfr[FN];
#pragma unroll
        for (int f = 0; f < FM; f++) af[f] = *(const bf16x8*)&As[arow_lds[f]];
#pragma unroll
        for (int f = 0; f < FN; f++) bfr[f] = *(const bf16x8*)&Bs[brow_lds[f]];
#pragma unroll
        for (int fm = 0; fm < FM; fm++)
#pragma unroll
            for (int fn = 0; fn < FN; fn++)
                acc[fm][fn] = __builtin_amdgcn_mfma_f32_16x16x32_bf16(
                    af[fm], bfr[fn], acc[fm][fn], 0, 0, 0);
    }

#pragma unroll
    for (int fm = 0; fm < FM; fm++) {
#pragma unroll
        for (int r = 0; r < 4; r++) {
            int row = m0 + wr * (TM / 2) + fm * 16 + ((lane >> 4) << 2) + r;
            size_t orow;
            if (OMAP) {
                int bc = row >> 10, rr = row & 1023;
                int b = bc >> 2, c = bc & 3;
                orow = ((size_t)(b * RR + rr)) * CC + c;
            } else orow = (size_t)row;
#pragma unroll
            for (int fn = 0; fn < FN; fn++) {
                int col = n0 + wc * (TN / 2) + fn * 16 + (lane & 15);
                float v = acc[fm][fn][r];
                if (BIAS) v += bias[col];
                if (GELU) v = 0.5f * v * (1.0f + erff(v * 0.70710678118654752f));
                if (RES)  v += res[(size_t)row * N + col];
                if (OUTBF) Ch[orow * (size_t)N + col] = f2b(v);
                else       Cf[orow * (size_t)N + col] = v;
            }
        }
    }
}

// ---------------------------------------------------------------------------
// Feature attention: seq len 4, per (b,r) block. Reads qkv f32, writes bf16.
// ---------------------------------------------------------------------------
__global__ __launch_bounds__(256) void fa_attn(const float* __restrict__ qkv,
                                               unsigned short* __restrict__ outb)
{
    int seq = blockIdx.x, tid = threadIdx.x;
    __shared__ float sq[4][E_], sk[4][E_], sv[4][E_];
    __shared__ float ss[H_][4][4];
    __shared__ float sw[H_][4][4];
    for (int i = 0; i < 4; i++) {
        const float* srcp = qkv + ((size_t)(seq * 4 + i)) * 768;
        for (int idx = tid; idx < 768; idx += 256) {
            float v = srcp[idx];
            if (idx < 256) sq[i][idx] = v;
            else if (idx < 512) sk[i][idx - 256] = v;
            else sv[i][idx - 512] = v;
        }
    }
    __syncthreads();
    if (tid < 128) {
        int h = tid >> 4, i = (tid >> 2) & 3, j = tid & 3;
        float s = 0;
        for (int d = 0; d < DH; d++) s += sq[i][h * DH + d] * sk[j][h * DH + d];
        ss[h][i][j] = s * 0.17677669529663688f;   // 1/sqrt(32)
    }
    __syncthreads();
    if (tid < 32) {
        int h = tid >> 2, i = tid & 3;
        float m = ss[h][i][0];
        for (int j = 1; j < 4; j++) m = fmaxf(m, ss[h][i][j]);
        float e[4], sum = 0;
        for (int j = 0; j < 4; j++) { e[j] = expf(ss[h][i][j] - m); sum += e[j]; }
        float inv = 1.0f / sum;
        for (int j = 0; j < 4; j++) sw[h][i][j] = e[j] * inv;
    }
    __syncthreads();
    int e = tid, h = e >> 5;
    for (int i = 0; i < 4; i++) {
        float o = 0;
        for (int j = 0; j < 4; j++) o += sw[h][i][j] * sv[j][e];
        outb[((size_t)(seq * 4 + i)) * E_ + e] = f2b(o);
    }
}

// ---------------------------------------------------------------------------
// LayerNorm per 256-wide row. OMAP=1: token row -> st row (transpose).
// WB=1: also write bf16 copy.
// ---------------------------------------------------------------------------
template<int OMAP, int WB>
__global__ __launch_bounds__(64) void ln_k(const float* __restrict__ in,
                                           const float* __restrict__ g,
                                           const float* __restrict__ bta,
                                           float* __restrict__ out,
                                           unsigned short* __restrict__ outh)
{
    int row = blockIdx.x, t = threadIdx.x;
    float4 v = ((const float4*)(in + (size_t)row * E_))[t];
    float s = v.x + v.y + v.z + v.w;
#pragma unroll
    for (int o = 32; o >= 1; o >>= 1) s += __shfl_xor(s, o);
    float mean = s * (1.0f / E_);
    float dx0 = v.x - mean, dx1 = v.y - mean, dx2 = v.z - mean, dx3 = v.w - mean;
    float q = dx0 * dx0 + dx1 * dx1 + dx2 * dx2 + dx3 * dx3;
#pragma unroll
    for (int o = 32; o >= 1; o >>= 1) q += __shfl_xor(q, o);
    float inv = rsqrtf(q * (1.0f / E_) + 1e-5f);
    size_t orow;
    if (OMAP == 1) {
        int b = row >> 12, r = (row >> 2) & 1023, c = row & 3;
        orow = ((size_t)(b * CC + c)) * RR + r;
    } else orow = (size_t)row;
    int c0 = t * 4;
    float4 o;
    o.x = dx0 * inv * g[c0 + 0] + bta[c0 + 0];
    o.y = dx1 * inv * g[c0 + 1] + bta[c0 + 1];
    o.z = dx2 * inv * g[c0 + 2] + bta[c0 + 2];
    o.w = dx3 * inv * g[c0 + 3] + bta[c0 + 3];
    ((float4*)(out + orow * E_))[t] = o;
    if (WB) {
        ushort4 oh; oh.x = f2b(o.x); oh.y = f2b(o.y); oh.z = f2b(o.z); oh.w = f2b(o.w);
        ((ushort4*)(outh + orow * E_))[t] = oh;
    }
}

// ---------------------------------------------------------------------------
// Indexer projections: q32 / k32 = st_row @ {idx_q_w, idx_k_w}^T  (32 each)
// ---------------------------------------------------------------------------
__global__ __launch_bounds__(256) void idx_proj(const float* __restrict__ st,
                                                const float* __restrict__ qw,
                                                const float* __restrict__ kw,
                                                float* __restrict__ q32,
                                                float* __restrict__ k32)
{
    int row = blockIdx.x, tid = threadIdx.x;
    __shared__ float sx[E_];
    sx[tid] = st[(size_t)row * E_ + tid];
    __syncthreads();
    int d = tid >> 2, sub = tid & 3;
    const float* w = (d < 32) ? (qw + (size_t)d * E_) : (kw + (size_t)(d - 32) * E_);
    float s = 0;
    for (int k = sub; k < E_; k += 4) s += w[k] * sx[k];
    s += __shfl_xor(s, 1); s += __shfl_xor(s, 2);
    if (sub == 0) {
        if (d < 32) q32[(size_t)row * 32 + d] = s;
        else        k32[(size_t)row * 32 + (d - 32)] = s;
    }
}

// ---------------------------------------------------------------------------
// Indexer scales: 96 blocks = type(0 q-train,1 q-test,2 k-train) x bf x h
// ---------------------------------------------------------------------------
__global__ __launch_bounds__(256) void idx_scales(const float* __restrict__ q32,
                                                  const float* __restrict__ k32,
                                                  float* __restrict__ scl)
{
    int id = blockIdx.x;
    int type = id / 32, bf = (id % 32) >> 2, h = id & 3;
    const float* src = (type == 2) ? k32 : q32;
    int r0 = (type == 1) ? SPLIT : 0;
    int r1 = (type == 1) ? RR : SPLIT;
    float m = 0;
    for (int r = r0 + (int)threadIdx.x; r < r1; r += 256) {
        const float* p = src + ((size_t)(bf * RR + r)) * 32 + h * 8;
        for (int dd = 0; dd < 8; dd++) m = fmaxf(m, fabsf(p[dd]));
    }
#pragma unroll
    for (int o = 32; o >= 1; o >>= 1) m = fmaxf(m, __shfl_xor(m, o));
    __shared__ float red[4];
    if ((threadIdx.x & 63) == 0) red[threadIdx.x >> 6] = m;
    __syncthreads();
    if (threadIdx.x == 0) {
        m = fmaxf(fmaxf(red[0], red[1]), fmaxf(red[2], red[3]));
        scl[id] = (m + 1e-6f) / 127.0f;
    }
}

// ---------------------------------------------------------------------------
// Quantize k (train rows only) to int8
// ---------------------------------------------------------------------------
__global__ __launch_bounds__(256) void idx_quantk(const float* __restrict__ k32,
                                                  const float* __restrict__ scl,
                                                  signed char* __restrict__ ki8)
{
    int gi = blockIdx.x * 256 + threadIdx.x;     // 0 .. 8*768*32-1
    int bf = gi / (SPLIT * 32);
    int rem = gi % (SPLIT * 32);
    int r = rem >> 5, d = rem & 31, h = d >> 3;
    float ks = scl[64 + bf * 4 + h];
    float v = k32[((size_t)(bf * RR + r)) * 32 + d];
    float qq = fminf(fmaxf(rintf(v / ks), -127.f), 127.f);
    ki8[gi] = (signed char)qq;
}

// ---------------------------------------------------------------------------
// Indexer scores + top-32. Ties -> smallest index (jax.lax.top_k semantics).
// Selection via fully-parallel rank-count over unique u64 keys; the u64
// strict-> compare+count is hand-lowered to the 3-instruction borrow chain
// (v_sub_co / v_subb_co / v_addc_co) — exact, branch-free, full-rate.
// ---------------------------------------------------------------------------
__device__ __forceinline__ void cmp3_count(
    unsigned klo, unsigned khi,
    unsigned a0lo, unsigned a0hi, unsigned a1lo, unsigned a1hi,
    unsigned a2lo, unsigned a2hi, int& c0, int& c1, int& c2)
{
    unsigned scr;
    asm volatile(
        "v_sub_co_u32 %[s], vcc, %[a0l], %[kl]\n\t"
        "v_subb_co_u32 %[s], vcc, %[a0h], %[kh], vcc\n\t"
        "v_addc_co_u32 %[c0], vcc, 0, %[c0], vcc\n\t"
        "v_sub_co_u32 %[s], vcc, %[a1l], %[kl]\n\t"
        "v_subb_co_u32 %[s], vcc, %[a1h], %[kh], vcc\n\t"
        "v_addc_co_u32 %[c1], vcc, 0, %[c1], vcc\n\t"
        "v_sub_co_u32 %[s], vcc, %[a2l], %[kl]\n\t"
        "v_subb_co_u32 %[s], vcc, %[a2h], %[kh], vcc\n\t"
        "v_addc_co_u32 %[c2], vcc, 0, %[c2], vcc"
        : [c0]"+v"(c0), [c1]"+v"(c1), [c2]"+v"(c2), [s]"=&v"(scr)
        : [kl]"v"(klo), [kh]"v"(khi),
          [a0l]"v"(a0lo), [a0h]"v"(a0hi),
          [a1l]"v"(a1lo), [a1h]"v"(a1hi),
          [a2l]"v"(a2lo), [a2h]"v"(a2hi)
        : "vcc");
}

__device__ __forceinline__ void cmp1_count2(
    unsigned k0lo, unsigned k0hi, unsigned k1lo, unsigned k1hi,
    unsigned alo, unsigned ahi, int& c)
{
    unsigned scr;
    asm volatile(
        "v_sub_co_u32 %[s], vcc, %[al], %[k0l]\n\t"
        "v_subb_co_u32 %[s], vcc, %[ah], %[k0h], vcc\n\t"
        "v_addc_co_u32 %[c], vcc, 0, %[c], vcc\n\t"
        "v_sub_co_u32 %[s], vcc, %[al], %[k1l]\n\t"
        "v_subb_co_u32 %[s], vcc, %[ah], %[k1h], vcc\n\t"
        "v_addc_co_u32 %[c], vcc, 0, %[c], vcc"
        : [c]"+v"(c), [s]"=&v"(scr)
        : [k0l]"v"(k0lo), [k0h]"v"(k0hi), [k1l]"v"(k1lo), [k1h]"v"(k1hi),
          [al]"v"(alo), [ah]"v"(ahi)
        : "vcc");
}

__global__ __launch_bounds__(256) void idx_score_topk(const float* __restrict__ q32,
                                                      const signed char* __restrict__ ki8,
                                                      const float* __restrict__ scl,
                                                      const float* __restrict__ ow,
                                                      int* __restrict__ idx_out)
{
    int bid = blockIdx.x, tid = threadIdx.x;
    int bf = bid >> 10, qr = bid & 1023;
    int sel = (qr < SPLIT) ? 0 : 32;
    __shared__ float qi[32];
    __shared__ float fac[4];
    __shared__ __align__(16) unsigned long long keys[SPLIT];
    __shared__ __align__(16) unsigned long long warr[4][32];
    if (tid < 32) {
        int h = tid >> 3;
        float qs = scl[sel + bf * 4 + h];
        float v = q32[((size_t)bid) * 32 + tid];
        qi[tid] = fminf(fmaxf(rintf(v / qs), -127.f), 127.f);
    }
    if (tid < 4) {
        float qs = scl[sel + bf * 4 + tid];
        float ks = scl[64 + bf * 4 + tid];
        fac[tid] = __fmul_rn(qs, ks);
    }
    __syncthreads();
    float ow0 = ow[0], ow1 = ow[1], ow2 = ow[2], ow3 = ow[3];
    for (int k = tid; k < SPLIT; k += 256) {
        const int4* kp4 = (const int4*)(ki8 + ((size_t)(bf * SPLIT + k)) * 32);
        int4 w0 = kp4[0], w1 = kp4[1];
        int wd[8] = {w0.x, w0.y, w0.z, w0.w, w1.x, w1.y, w1.z, w1.w};
        float owv[4] = {ow0, ow1, ow2, ow3};
        float r = 0;
#pragma unroll
        for (int h = 0; h < 4; h++) {
            float dot = 0.f;
#pragma unroll
            for (int b = 0; b < 2; b++) {
                unsigned int w = (unsigned int)wd[h * 2 + b];
#pragma unroll
                for (int by = 0; by < 4; by++) {
                    float kv = (float)((signed char)(w >> (8 * by)));
                    dot = fmaf(qi[h * 8 + b * 4 + by], kv, dot);
                }
            }
            float sc = fmaxf(__fmul_rn(dot, fac[h]), 0.f);
            r = __fadd_rn(r, __fmul_rn(sc, owv[h]));
        }
        unsigned int bitsv = __float_as_uint(r);
        unsigned int mono = (bitsv & 0x80000000u) ? ~bitsv : (bitsv | 0x80000000u);
        if (mono == 0x7FFFFFFFu) mono = 0x80000000u;   // canonicalize -0 == +0
        keys[k] = ((unsigned long long)mono << 32) | (unsigned int)(1023 - k);
    }
    __syncthreads();
    // stage 1: per-wave rank-count top-32 (parallel, broadcast LDS reads)
    {
        int w = tid >> 6, lane = tid & 63;
        const unsigned long long* kb = &keys[w * 192];
        unsigned long long A0 = kb[lane];
        unsigned long long A1 = kb[64 + lane];
        unsigned long long A2 = kb[128 + lane];
        unsigned a0lo = (unsigned)A0, a0hi = (unsigned)(A0 >> 32);
        unsigned a1lo = (unsigned)A1, a1hi = (unsigned)(A1 >> 32);
        unsigned a2lo = (unsigned)A2, a2hi = (unsigned)(A2 >> 32);
        int c0 = 0, c1 = 0, c2 = 0;
        const uint4* kb4 = (const uint4*)kb;
#pragma unroll 4
        for (int j = 0; j < 96; j++) {
            uint4 kk = kb4[j];
            cmp3_count(kk.x, kk.y, a0lo, a0hi, a1lo, a1hi, a2lo, a2hi, c0, c1, c2);
            cmp3_count(kk.z, kk.w, a0lo, a0hi, a1lo, a1hi, a2lo, a2hi, c0, c1, c2);
        }
        if (c0 < TOPK_) warr[w][c0] = A0;
        if (c1 < TOPK_) warr[w][c1] = A1;
        if (c2 < TOPK_) warr[w][c2] = A2;
    }
    __syncthreads();
    // stage 2: merge 4x32 -> global top-32 via rank-count
    if (tid < 128) {
        unsigned long long mine = (&warr[0][0])[tid];
        unsigned mlo = (unsigned)mine, mhi = (unsigned)(mine >> 32);
        const uint4* wf4 = (const uint4*)&warr[0][0];
        int r = 0;
#pragma unroll 4
        for (int j = 0; j < 64; j++) {
            uint4 kk = wf4[j];
            cmp1_count2(kk.x, kk.y, kk.z, kk.w, mlo, mhi, r);
        }
        if (r < TOPK_)
            idx_out[(size_t)bid * TOPK_ + r] = 1023 - (int)(unsigned int)(mine & 0xFFFFFFFFull);
    }
}

// ---------------------------------------------------------------------------
// MLA absorption part 1: G[q][h][l] = sum_d qb[q][h*32+d] * up_w[h*32+d][l]
// ---------------------------------------------------------------------------
__global__ __launch_bounds__(256) void mla_g(const float* __restrict__ qb,
                                             const float* __restrict__ uw,
                                             float* __restrict__ G)
{
    int qt = blockIdx.x, h = blockIdx.y, tid = threadIdx.x;
    __shared__ float Qs[64][33];
    __shared__ float Us[32][132];
    {
        int r = tid >> 2, c0 = (tid & 3) * 8;
        const float* srcp = qb + ((size_t)(qt * 64 + r)) * E_ + h * DH + c0;
        float4 a = ((const float4*)srcp)[0];
        float4 b = ((const float4*)srcp)[1];
        Qs[r][c0 + 0] = a.x; Qs[r][c0 + 1] = a.y; Qs[r][c0 + 2] = a.z; Qs[r][c0 + 3] = a.w;
        Qs[r][c0 + 4] = b.x; Qs[r][c0 + 5] = b.y; Qs[r][c0 + 6] = b.z; Qs[r][c0 + 7] = b.w;
    }
    {
        int d = tid >> 3, l0 = (tid & 7) * 16;
        const float* srcp = uw + (size_t)(h * DH + d) * LATD + l0;
#pragma unroll
        for (int ii = 0; ii < 4; ii++) {
            float4 v = ((const float4*)srcp)[ii];
            *(float4*)&Us[d][l0 + ii * 4] = v;
        }
    }
    __syncthreads();
    int rg = tid >> 5, l = (tid & 31) * 4;
    float acc[8][4];
#pragma unroll
    for (int i = 0; i < 8; i++)
#pragma unroll
        for (int j = 0; j < 4; j++) acc[i][j] = 0.f;
    for (int d = 0; d < DH; d++) {
        float4 u = *(const float4*)&Us[d][l];
#pragma unroll
        for (int i = 0; i < 8; i++) {
            float qv = Qs[rg * 8 + i][d];
            acc[i][0] += qv * u.x; acc[i][1] += qv * u.y;
            acc[i][2] += qv * u.z; acc[i][3] += qv * u.w;
        }
    }
#pragma unroll
    for (int i = 0; i < 8; i++) {
        float4 o = {acc[i][0], acc[i][1], acc[i][2], acc[i][3]};
        *(float4*)(G + ((size_t)(qt * 64 + rg * 8 + i)) * 1024 + h * 128 + l) = o;
    }
}

// ---------------------------------------------------------------------------
// Fused sparse MLA attention per (bf, q)
// ---------------------------------------------------------------------------
__global__ __launch_bounds__(256) void mla_attn(const float* __restrict__ G,
                                                const float* __restrict__ cb,
                                                const int* __restrict__ idxb,
                                                float* __restrict__ Mo)
{
    int bid = blockIdx.x, tid = threadIdx.x;
    int bf = bid >> 10;
    __shared__ float cs[32][132];
    __shared__ float gs[8][132];
    __shared__ float swt[32][8];
    __shared__ int sidx[32];
    if (tid < 32) sidx[tid] = idxb[(size_t)bid * 32 + tid];
    {
        int flat = tid * 4, h = flat >> 7, l = flat & 127;
        float4 gv = *(const float4*)(G + (size_t)bid * 1024 + flat);
        *(float4*)&gs[h][l] = gv;
    }
    __syncthreads();
    {
        int j = tid >> 3, l0 = (tid & 7) * 16;
        const float* srcp = cb + ((size_t)(bf * SPLIT + sidx[j])) * LATD + l0;
#pragma unroll
        for (int ii = 0; ii < 4; ii++) {
            float4 vv = ((const float4*)srcp)[ii];
            *(float4*)&cs[j][l0 + ii * 4] = vv;
        }
    }
    __syncthreads();
    {
        int j = tid >> 3, h = tid & 7;
        float s = 0;
#pragma unroll
        for (int lb = 0; lb < 32; lb++) {
            float4 c4 = *(const float4*)&cs[j][lb * 4];
            float4 g4 = *(const float4*)&gs[h][lb * 4];
            s += c4.x * g4.x + c4.y * g4.y + c4.z * g4.z + c4.w * g4.w;
        }
        swt[j][h] = s * 0.17677669529663688f;
    }
    __syncthreads();
    if (tid < 8) {
        float m = swt[0][tid];
        for (int j = 1; j < 32; j++) m = fmaxf(m, swt[j][tid]);
        float sum = 0;
        for (int j = 0; j < 32; j++) { float e = expf(swt[j][tid] - m); swt[j][tid] = e; sum += e; }
        float inv = 1.0f / sum;
        for (int j = 0; j < 32; j++) swt[j][tid] *= inv;
    }
    __syncthreads();
    {
        int flat = tid * 4, h = flat >> 7, l = flat & 127;
        float4 acc = {0, 0, 0, 0};
        for (int j = 0; j < 32; j++) {
            float w = swt[j][h];
            float4 c4 = *(const float4*)&cs[j][l];
            acc.x += w * c4.x; acc.y += w * c4.y; acc.z += w * c4.z; acc.w += w * c4.w;
        }
        *(float4*)(Mo + (size_t)bid * 1024 + flat) = acc;
    }
}

// ---------------------------------------------------------------------------
// MLA absorption part 2 -> bf16 output (consumed by out-proj GEMM)
// ---------------------------------------------------------------------------
__global__ __launch_bounds__(256) void mla_out(const float* __restrict__ Mo,
                                               const float* __restrict__ uw,
                                               unsigned short* __restrict__ ob)
{
    int qt = blockIdx.x, h = blockIdx.y, tid = threadIdx.x;
    __shared__ float Ms[64][132];
    __shared__ float Us[32][129];
    {
        int r = tid >> 2, l0 = (tid & 3) * 32;
        const float* srcp = Mo + ((size_t)(qt * 64 + r)) * 1024 + h * 128 + l0;
#pragma unroll
        for (int ii = 0; ii < 8; ii++) {
            float4 v = ((const float4*)srcp)[ii];
            *(float4*)&Ms[r][l0 + ii * 4] = v;
        }
    }
    {
        int d = tid >> 3, l0 = (tid & 7) * 16;
        const float* srcp = uw + (size_t)(256 + h * DH + d) * LATD + l0;
#pragma unroll
        for (int ii = 0; ii < 4; ii++) {
            float4 v = ((const float4*)srcp)[ii];
            Us[d][l0 + ii * 4 + 0] = v.x; Us[d][l0 + ii * 4 + 1] = v.y;
            Us[d][l0 + ii * 4 + 2] = v.z; Us[d][l0 + ii * 4 + 3] = v.w;
        }
    }
    __syncthreads();
    int d = tid & 31, rg = tid >> 5;
    float acc[8] = {0, 0, 0, 0, 0, 0, 0, 0};
    for (int l = 0; l < 128; l++) {
        float u = Us[d][l];
#pragma unroll
        for (int i = 0; i < 8; i++) acc[i] += Ms[rg * 8 + i][l] * u;
    }
#pragma unroll
    for (int i = 0; i < 8; i++)
        ob[((size_t)(qt * 64 + rg * 8 + i)) * E_ + h * DH + d] = f2b(acc[i]);
}

// ---------------------------------------------------------------------------
extern "C" void kernel_launch(void* const* d_in, const int* in_sizes, int n_in,
                              void* d_out, int out_size, void* d_ws, size_t ws_size,
                              hipStream_t stream)
{
    (void)in_sizes; (void)n_in; (void)out_size; (void)ws_size;
    const float* src      = (const float*)d_in[0];
    const float* fa_in_w  = (const float*)d_in[2];
    const float* fa_in_b  = (const float*)d_in[3];
    const float* fa_out_w = (const float*)d_in[4];
    const float* fa_out_b = (const float*)d_in[5];
    const float* n1g = (const float*)d_in[6];
    const float* n1b = (const float*)d_in[7];
    const float* iqw = (const float*)d_in[8];
    const float* ikw = (const float*)d_in[9];
    const float* iow = (const float*)d_in[10];
    const float* mqw = (const float*)d_in[11];
    const float* mdw = (const float*)d_in[12];
    const float* muw = (const float*)d_in[13];
    const float* mow = (const float*)d_in[14];
    const float* n2g = (const float*)d_in[15];
    const float* n2b = (const float*)d_in[16];
    const float* l1w = (const float*)d_in[17];
    const float* l1b = (const float*)d_in[18];
    const float* l2w = (const float*)d_in[19];
    const float* l2b = (const float*)d_in[20];
    const float* n3g = (const float*)d_in[21];
    const float* n3b = (const float*)d_in[22];

    float* ws = (float*)d_ws;
    size_t off = 0;
    auto alloc = [&](size_t n) { float* p = ws + off; off += (n + 3) & ~(size_t)3; return p; };

    float* bigA = alloc((size_t)NT * 1024);   // qkv -> G -> x2 (first NT*256)
    float* Mh   = alloc((size_t)NT * 1024);   // M f32; later h1 bf16 (inside)
    float* tbuf = alloc((size_t)NT * E_);     // pre-LN buf; doubles as qb (10-11)
    float* stb  = alloc((size_t)NT * E_);     // st f32 (post-LN1, transposed)
    float* cb   = alloc((size_t)BF * SPLIT * LATD);
    unsigned short* actBF1 = (unsigned short*)alloc((size_t)NT * E_ / 2); // src16/abuf16/stb16
    unsigned short* actBF2 = (unsigned short*)alloc((size_t)NT * E_ / 2); // ob16/x216
    float* q32 = alloc((size_t)NT * 32);
    float* k32 = alloc((size_t)NT * 32);
    float* scl = alloc(128);
    int*   idxb = (int*)alloc((size_t)NT * 32);
    signed char* ki8 = (signed char*)alloc((size_t)NT * 32 / 4);
    unsigned short* w16 = (unsigned short*)alloc(950272 / 2 + 8);

    unsigned short* fa_in_w16  = w16;
    unsigned short* fa_out_w16 = fa_in_w16 + 196608;
    unsigned short* mqw16      = fa_out_w16 + 65536;
    unsigned short* mdw16      = mqw16 + 65536;
    unsigned short* mow16      = mdw16 + 32768;
    unsigned short* l1w16      = mow16 + 65536;
    unsigned short* l2w16      = l1w16 + 262144;

    float* qkv = bigA;
    float* G   = bigA;
    float* x2  = bigA;                        // LN2 out (alive after G dead)
    float* Mbuf = Mh;
    unsigned short* h116 = (unsigned short*)Mh;
    float* qb = tbuf;
    unsigned short* src16  = actBF1;
    unsigned short* abuf16 = actBF1;
    unsigned short* stb16  = actBF1;
    unsigned short* ob16   = actBF2;
    unsigned short* x216   = actBF2;

    // 0. convert weights + src to bf16
    ConvArgs ca;
    const float* segs[8] = {src, fa_in_w, fa_out_w, mqw, mdw, mow, l1w, l2w};
    unsigned short* segd[8] = {src16, fa_in_w16, fa_out_w16, mqw16, mdw16, mow16, l1w16, l2w16};
    int segn[8] = {NT * E_, 196608, 65536, 65536, 32768, 65536, 262144, 262144};
    int cum = 0;
    for (int i = 0; i < 8; i++) { ca.s[i] = segs[i]; ca.d[i] = segd[i]; cum += segn[i] / 4; ca.cum[i] = cum; }
    int totq = cum;
    convert_f2b<<<(totq + 255) / 256, 256, 0, stream>>>(ca, totq);

    dim3 blk(256);
    // 1. qkv = src @ fa_in_w^T + b
    gemm_mfma<128,128,1,0,0,0,0,0><<<dim3(6,64), blk, 0, stream>>>(src16, fa_in_w16, fa_in_b, nullptr, qkv, nullptr, NT, 768, 256);
    // 2. feature attention (S=4) -> bf16
    fa_attn<<<2048, blk, 0, stream>>>(qkv, abuf16);
    // 3. out-proj + bias + residual(src)
    gemm_mfma<128,64,1,0,1,0,0,0><<<dim3(4,64), blk, 0, stream>>>(abuf16, fa_out_w16, fa_out_b, src, tbuf, nullptr, NT, 256, 256);
    // 4. LN1, write transposed f32 + bf16
    ln_k<1,1><<<NT, dim3(64), 0, stream>>>(tbuf, n1g, n1b, stb, stb16);
    // 5. indexer projections (exact f32)
    idx_proj<<<NT, blk, 0, stream>>>(stb, iqw, ikw, q32, k32);
    // 6. scales
    idx_scales<<<96, blk, 0, stream>>>(q32, k32, scl);
    // 7. quantize k
    idx_quantk<<<(BF * SPLIT * 32) / 256, blk, 0, stream>>>(k32, scl, ki8);
    // 8. scores + top-32
    idx_score_topk<<<NT, blk, 0, stream>>>(q32, ki8, scl, iow, idxb);
    // 9. c = x_tr @ down_w^T   (train rows only)
    gemm_mfma<64,64,0,0,0,1,0,0><<<dim3(2,96), blk, 0, stream>>>(stb16, mdw16, nullptr, nullptr, cb, nullptr, BF * SPLIT, 128, 256);
    // 10. mla q projection
    gemm_mfma<128,64,0,0,0,0,0,0><<<dim3(4,64), blk, 0, stream>>>(stb16, mqw16, nullptr, nullptr, qb, nullptr, NT, 256, 256);
    // 11. G = per-head up_w(K-half)^T @ q
    mla_g<<<dim3(128,8), blk, 0, stream>>>(qb, muw, G);
    // 12. fused sparse attention -> M
    mla_attn<<<NT, blk, 0, stream>>>(G, cb, idxb, Mbuf);
    // 13. out = per-head up_w(V-half) @ M -> bf16
    mla_out<<<dim3(128,8), blk, 0, stream>>>(Mbuf, muw, ob16);
    // 14. mla out-proj + residual(stb), scatter to BRCE token rows
    gemm_mfma<128,64,0,0,1,0,1,0><<<dim3(4,64), blk, 0, stream>>>(ob16, mow16, nullptr, stb, tbuf, nullptr, NT, 256, 256);
    // 15. LN2 -> x2 f32 + bf16
    ln_k<0,1><<<NT, dim3(64), 0, stream>>>(tbuf, n2g, n2b, x2, x216);
    // 16. MLP1 + GELU -> bf16 h1
    gemm_mfma<128,128,1,1,0,0,0,1><<<dim3(8,64), blk, 0, stream>>>(x216, l1w16, l1b, nullptr, nullptr, h116, NT, MLPD, 256);
    // 17. MLP2 + bias + residual(x2)
    gemm_mfma<128,64,1,0,1,0,0,0><<<dim3(4,64), blk, 0, stream>>>(h116, l2w16, l2b, x2, tbuf, nullptr, NT, 256, MLPD);
    // 18. LN3 -> output
    ln_k<0,0><<<NT, dim3(64), 0, stream>>>(tbuf, n3g, n3b, (float*)d_out, nullptr);
}

// Round 6
// 473.478 us; speedup vs baseline: 1.0217x; 1.0217x over previous
//
#include <hip/hip_runtime.h>
#include <hip/hip_bf16.h>
#include <cmath>

#define E_ 256
#define H_ 8
#define DH 32
#define MLPD 1024
#define LATD 128
#define TOPK_ 32
#define BB 2
#define RR 1024
#define CC 4
#define NT 8192      // B*R*C tokens
#define BF 8         // B*C
#define SPLIT 768

using bf16x8 = __attribute__((ext_vector_type(8))) short;
using f32x4v = __attribute__((ext_vector_type(4))) float;

__device__ __forceinline__ unsigned short f2b(float x) {
    __hip_bfloat16 h = __float2bfloat16(x);
    return *reinterpret_cast<unsigned short*>(&h);
}

// ---------------------------------------------------------------------------
// Fused f32 -> bf16 converter for weights + src (8 segments)
// ---------------------------------------------------------------------------
struct ConvArgs {
    const float* s[8];
    unsigned short* d[8];
    int cum[8];   // cumulative quad counts (exclusive prefix ends)
};
__global__ __launch_bounds__(256) void convert_f2b(ConvArgs a, int totq)
{
    int q = blockIdx.x * 256 + threadIdx.x;
    if (q >= totq) return;
    int seg = 0;
    while (q >= a.cum[seg]) seg++;
    int lq = q - (seg ? a.cum[seg - 1] : 0);
    float4 v = ((const float4*)a.s[seg])[lq];
    ushort4 o;
    o.x = f2b(v.x); o.y = f2b(v.y); o.z = f2b(v.z); o.w = f2b(v.w);
    ((ushort4*)a.d[seg])[lq] = o;
}

// ---------------------------------------------------------------------------
// bf16 MFMA GEMM: C[M][N] = A(MxK bf16) @ W(NxK bf16)^T (+bias)(+gelu)(+res f32)
// TMxTN tile, 4 waves (2x2), frags of 16x16x32.
// AMAP: A-row gather (train rows). OMAP: st-row -> BRCE token row scatter.
// OUTBF: write bf16 (Ch) instead of f32 (Cf).
// ---------------------------------------------------------------------------
template<int TM, int TN, int BIAS, int GELU, int RES, int AMAP, int OMAP, int OUTBF>
__global__ __launch_bounds__(256) void gemm_mfma(
    const unsigned short* __restrict__ A, const unsigned short* __restrict__ W,
    const float* __restrict__ bias, const float* __restrict__ res,
    float* __restrict__ Cf, unsigned short* __restrict__ Ch,
    int M, int N, int K)
{
    __shared__ __align__(16) unsigned short As[TM * 40];
    __shared__ __align__(16) unsigned short Bs[TN * 40];
    const int tid = threadIdx.x;
    const int lane = tid & 63, wave = tid >> 6;
    const int wr = wave >> 1, wc = wave & 1;
    const int m0 = blockIdx.y * TM, n0 = blockIdx.x * TN;

    // staging coordinates
    int ra, kqa;
    if constexpr (TM == 128) { ra = tid >> 1; kqa = (tid & 1) * 16; }
    else                     { ra = tid >> 2; kqa = (tid & 3) * 8; }
    int rb, kqb;
    if constexpr (TN == 128) { rb = tid >> 1; kqb = (tid & 1) * 16; }
    else                     { rb = tid >> 2; kqb = (tid & 3) * 8; }

    int am = m0 + ra;
    size_t arow = AMAP ? ((size_t)(am / SPLIT) * RR + (am % SPLIT)) : (size_t)am;
    const unsigned short* Ap = A + arow * (size_t)K + kqa;
    const unsigned short* Bp = W + (size_t)(n0 + rb) * K + kqb;

    constexpr int FM = TM / 32, FN = TN / 32;
    f32x4v acc[FM][FN];
#pragma unroll
    for (int i = 0; i < FM; i++)
#pragma unroll
        for (int j = 0; j < FN; j++) acc[i][j] = (f32x4v){0.f, 0.f, 0.f, 0.f};

    const int kof = (lane >> 4) * 8;
    int arow_lds[FM], brow_lds[FN];
#pragma unroll
    for (int f = 0; f < FM; f++)
        arow_lds[f] = (wr * (TM / 2) + f * 16 + (lane & 15)) * 40 + kof;
#pragma unroll
    for (int f = 0; f < FN; f++)
        brow_lds[f] = (wc * (TN / 2) + f * 16 + (lane & 15)) * 40 + kof;

    for (int k0 = 0; k0 < K; k0 += 32) {
        int4 va0, va1, vb0, vb1;
        va0 = *(const int4*)(Ap + k0);
        if constexpr (TM == 128) va1 = *(const int4*)(Ap + k0 + 8);
        vb0 = *(const int4*)(Bp + k0);
        if constexpr (TN == 128) vb1 = *(const int4*)(Bp + k0 + 8);
        __syncthreads();
        *(int4*)&As[ra * 40 + kqa] = va0;
        if constexpr (TM == 128) *(int4*)&As[ra * 40 + kqa + 8] = va1;
        *(int4*)&Bs[rb * 40 + kqb] = vb0;
        if constexpr (TN == 128) *(int4*)&Bs[rb * 40 + kqb + 8] = vb1;
        __syncthreads();
        bf16x8 af[FM], bfr[FN];
#pragma unroll
        for (int f = 0; f < FM; f++) af[f] = *(const bf16x8*)&As[arow_lds[f]];
#pragma unroll
        for (int f = 0; f < FN; f++) bfr[f] = *(const bf16x8*)&Bs[brow_lds[f]];
#pragma unroll
        for (int fm = 0; fm < FM; fm++)
#pragma unroll
            for (int fn = 0; fn < FN; fn++)
                acc[fm][fn] = __builtin_amdgcn_mfma_f32_16x16x32_bf16(
                    af[fm], bfr[fn], acc[fm][fn], 0, 0, 0);
    }

#pragma unroll
    for (int fm = 0; fm < FM; fm++) {
#pragma unroll
        for (int r = 0; r < 4; r++) {
            int row = m0 + wr * (TM / 2) + fm * 16 + ((lane >> 4) << 2) + r;
            size_t orow;
            if (OMAP) {
                int bc = row >> 10, rr = row & 1023;
                int b = bc >> 2, c = bc & 3;
                orow = ((size_t)(b * RR + rr)) * CC + c;
            } else orow = (size_t)row;
#pragma unroll
            for (int fn = 0; fn < FN; fn++) {
                int col = n0 + wc * (TN / 2) + fn * 16 + (lane & 15);
                float v = acc[fm][fn][r];
                if (BIAS) v += bias[col];
                if (GELU) v = 0.5f * v * (1.0f + erff(v * 0.70710678118654752f));
                if (RES)  v += res[(size_t)row * N + col];
                if (OUTBF) Ch[orow * (size_t)N + col] = f2b(v);
                else       Cf[orow * (size_t)N + col] = v;
            }
        }
    }
}

// ---------------------------------------------------------------------------
// Feature attention: seq len 4, per (b,r) block. Reads qkv f32, writes bf16.
// ---------------------------------------------------------------------------
__global__ __launch_bounds__(256) void fa_attn(const float* __restrict__ qkv,
                                               unsigned short* __restrict__ outb)
{
    int seq = blockIdx.x, tid = threadIdx.x;
    __shared__ float sq[4][E_], sk[4][E_], sv[4][E_];
    __shared__ float ss[H_][4][4];
    __shared__ float sw[H_][4][4];
    for (int i = 0; i < 4; i++) {
        const float* srcp = qkv + ((size_t)(seq * 4 + i)) * 768;
        for (int idx = tid; idx < 768; idx += 256) {
            float v = srcp[idx];
            if (idx < 256) sq[i][idx] = v;
            else if (idx < 512) sk[i][idx - 256] = v;
            else sv[i][idx - 512] = v;
        }
    }
    __syncthreads();
    if (tid < 128) {
        int h = tid >> 4, i = (tid >> 2) & 3, j = tid & 3;
        float s = 0;
        for (int d = 0; d < DH; d++) s += sq[i][h * DH + d] * sk[j][h * DH + d];
        ss[h][i][j] = s * 0.17677669529663688f;   // 1/sqrt(32)
    }
    __syncthreads();
    if (tid < 32) {
        int h = tid >> 2, i = tid & 3;
        float m = ss[h][i][0];
        for (int j = 1; j < 4; j++) m = fmaxf(m, ss[h][i][j]);
        float e[4], sum = 0;
        for (int j = 0; j < 4; j++) { e[j] = expf(ss[h][i][j] - m); sum += e[j]; }
        float inv = 1.0f / sum;
        for (int j = 0; j < 4; j++) sw[h][i][j] = e[j] * inv;
    }
    __syncthreads();
    int e = tid, h = e >> 5;
    for (int i = 0; i < 4; i++) {
        float o = 0;
        for (int j = 0; j < 4; j++) o += sw[h][i][j] * sv[j][e];
        outb[((size_t)(seq * 4 + i)) * E_ + e] = f2b(o);
    }
}

// ---------------------------------------------------------------------------
// LayerNorm per 256-wide row. OMAP=1: token row -> st row (transpose).
// WB=1: also write bf16 copy.
// ---------------------------------------------------------------------------
template<int OMAP, int WB>
__global__ __launch_bounds__(64) void ln_k(const float* __restrict__ in,
                                           const float* __restrict__ g,
                                           const float* __restrict__ bta,
                                           float* __restrict__ out,
                                           unsigned short* __restrict__ outh)
{
    int row = blockIdx.x, t = threadIdx.x;
    float4 v = ((const float4*)(in + (size_t)row * E_))[t];
    float s = v.x + v.y + v.z + v.w;
#pragma unroll
    for (int o = 32; o >= 1; o >>= 1) s += __shfl_xor(s, o);
    float mean = s * (1.0f / E_);
    float dx0 = v.x - mean, dx1 = v.y - mean, dx2 = v.z - mean, dx3 = v.w - mean;
    float q = dx0 * dx0 + dx1 * dx1 + dx2 * dx2 + dx3 * dx3;
#pragma unroll
    for (int o = 32; o >= 1; o >>= 1) q += __shfl_xor(q, o);
    float inv = rsqrtf(q * (1.0f / E_) + 1e-5f);
    size_t orow;
    if (OMAP == 1) {
        int b = row >> 12, r = (row >> 2) & 1023, c = row & 3;
        orow = ((size_t)(b * CC + c)) * RR + r;
    } else orow = (size_t)row;
    int c0 = t * 4;
    float4 o;
    o.x = dx0 * inv * g[c0 + 0] + bta[c0 + 0];
    o.y = dx1 * inv * g[c0 + 1] + bta[c0 + 1];
    o.z = dx2 * inv * g[c0 + 2] + bta[c0 + 2];
    o.w = dx3 * inv * g[c0 + 3] + bta[c0 + 3];
    ((float4*)(out + orow * E_))[t] = o;
    if (WB) {
        ushort4 oh; oh.x = f2b(o.x); oh.y = f2b(o.y); oh.z = f2b(o.z); oh.w = f2b(o.w);
        ((ushort4*)(outh + orow * E_))[t] = oh;
    }
}

// ---------------------------------------------------------------------------
// Indexer projections: q32 / k32 = st_row @ {idx_q_w, idx_k_w}^T  (32 each)
// ---------------------------------------------------------------------------
__global__ __launch_bounds__(256) void idx_proj(const float* __restrict__ st,
                                                const float* __restrict__ qw,
                                                const float* __restrict__ kw,
                                                float* __restrict__ q32,
                                                float* __restrict__ k32)
{
    int row = blockIdx.x, tid = threadIdx.x;
    __shared__ float sx[E_];
    sx[tid] = st[(size_t)row * E_ + tid];
    __syncthreads();
    int d = tid >> 2, sub = tid & 3;
    const float* w = (d < 32) ? (qw + (size_t)d * E_) : (kw + (size_t)(d - 32) * E_);
    float s = 0;
    for (int k = sub; k < E_; k += 4) s += w[k] * sx[k];
    s += __shfl_xor(s, 1); s += __shfl_xor(s, 2);
    if (sub == 0) {
        if (d < 32) q32[(size_t)row * 32 + d] = s;
        else        k32[(size_t)row * 32 + (d - 32)] = s;
    }
}

// ---------------------------------------------------------------------------
// Indexer scales: 96 blocks = type(0 q-train,1 q-test,2 k-train) x bf x h
// ---------------------------------------------------------------------------
__global__ __launch_bounds__(256) void idx_scales(const float* __restrict__ q32,
                                                  const float* __restrict__ k32,
                                                  float* __restrict__ scl)
{
    int id = blockIdx.x;
    int type = id / 32, bf = (id % 32) >> 2, h = id & 3;
    const float* src = (type == 2) ? k32 : q32;
    int r0 = (type == 1) ? SPLIT : 0;
    int r1 = (type == 1) ? RR : SPLIT;
    float m = 0;
    for (int r = r0 + (int)threadIdx.x; r < r1; r += 256) {
        const float* p = src + ((size_t)(bf * RR + r)) * 32 + h * 8;
        for (int dd = 0; dd < 8; dd++) m = fmaxf(m, fabsf(p[dd]));
    }
#pragma unroll
    for (int o = 32; o >= 1; o >>= 1) m = fmaxf(m, __shfl_xor(m, o));
    __shared__ float red[4];
    if ((threadIdx.x & 63) == 0) red[threadIdx.x >> 6] = m;
    __syncthreads();
    if (threadIdx.x == 0) {
        m = fmaxf(fmaxf(red[0], red[1]), fmaxf(red[2], red[3]));
        scl[id] = (m + 1e-6f) / 127.0f;
    }
}

// ---------------------------------------------------------------------------
// Quantize k (train rows only) to int8
// ---------------------------------------------------------------------------
__global__ __launch_bounds__(256) void idx_quantk(const float* __restrict__ k32,
                                                  const float* __restrict__ scl,
                                                  signed char* __restrict__ ki8)
{
    int gi = blockIdx.x * 256 + threadIdx.x;     // 0 .. 8*768*32-1
    int bf = gi / (SPLIT * 32);
    int rem = gi % (SPLIT * 32);
    int r = rem >> 5, d = rem & 31, h = d >> 3;
    float ks = scl[64 + bf * 4 + h];
    float v = k32[((size_t)(bf * RR + r)) * 32 + d];
    float qq = fminf(fmaxf(rintf(v / ks), -127.f), 127.f);
    ki8[gi] = (signed char)qq;
}

// ---------------------------------------------------------------------------
// Indexer scores + top-32. Ties -> smallest index (jax.lax.top_k semantics).
// Keys are exact-integer f64: mono_f32 * 1024 + (1023-k)  (42 bits < 53).
// f64 ordering == integer ordering == (value desc, index asc). The f64
// strict-> compare is a single native VOPC (v_cmp_gt_f64) + addc.
// Selection via fully-parallel rank-count (ranks unique -> permutation).
// ---------------------------------------------------------------------------
__global__ __launch_bounds__(256) void idx_score_topk(const float* __restrict__ q32,
                                                      const signed char* __restrict__ ki8,
                                                      const float* __restrict__ scl,
                                                      const float* __restrict__ ow,
                                                      int* __restrict__ idx_out)
{
    int bid = blockIdx.x, tid = threadIdx.x;
    int bf = bid >> 10, qr = bid & 1023;
    int sel = (qr < SPLIT) ? 0 : 32;
    __shared__ float qi[32];
    __shared__ float fac[4];
    __shared__ __align__(16) double keys[SPLIT];
    __shared__ __align__(16) double warr[4][32];
    if (tid < 32) {
        int h = tid >> 3;
        float qs = scl[sel + bf * 4 + h];
        float v = q32[((size_t)bid) * 32 + tid];
        qi[tid] = fminf(fmaxf(rintf(v / qs), -127.f), 127.f);
    }
    if (tid < 4) {
        float qs = scl[sel + bf * 4 + tid];
        float ks = scl[64 + bf * 4 + tid];
        fac[tid] = __fmul_rn(qs, ks);
    }
    __syncthreads();
    float ow0 = ow[0], ow1 = ow[1], ow2 = ow[2], ow3 = ow[3];
    for (int k = tid; k < SPLIT; k += 256) {
        const int4* kp4 = (const int4*)(ki8 + ((size_t)(bf * SPLIT + k)) * 32);
        int4 w0 = kp4[0], w1 = kp4[1];
        int wd[8] = {w0.x, w0.y, w0.z, w0.w, w1.x, w1.y, w1.z, w1.w};
        float owv[4] = {ow0, ow1, ow2, ow3};
        float r = 0;
#pragma unroll
        for (int h = 0; h < 4; h++) {
            float dot = 0.f;
#pragma unroll
            for (int b = 0; b < 2; b++) {
                unsigned int w = (unsigned int)wd[h * 2 + b];
#pragma unroll
                for (int by = 0; by < 4; by++) {
                    float kv = (float)((signed char)(w >> (8 * by)));
                    dot = fmaf(qi[h * 8 + b * 4 + by], kv, dot);
                }
            }
            float sc = fmaxf(__fmul_rn(dot, fac[h]), 0.f);
            r = __fadd_rn(r, __fmul_rn(sc, owv[h]));
        }
        unsigned int bitsv = __float_as_uint(r);
        unsigned int mono = (bitsv & 0x80000000u) ? ~bitsv : (bitsv | 0x80000000u);
        if (mono == 0x7FFFFFFFu) mono = 0x80000000u;   // canonicalize -0 == +0
        keys[k] = fma((double)mono, 1024.0, (double)(1023 - k));
    }
    __syncthreads();
    // stage 1: per-wave rank-count top-32 (parallel, broadcast LDS reads)
    {
        int w = tid >> 6, lane = tid & 63;
        const double* kb = &keys[w * 192];
        double A0 = kb[lane];
        double A1 = kb[64 + lane];
        double A2 = kb[128 + lane];
        int c0 = 0, c1 = 0, c2 = 0;
#pragma unroll 8
        for (int j = 0; j < 192; j += 2) {
            double k0 = kb[j], k1 = kb[j + 1];
            c0 += (k0 > A0); c0 += (k1 > A0);
            c1 += (k0 > A1); c1 += (k1 > A1);
            c2 += (k0 > A2); c2 += (k1 > A2);
        }
        if (c0 < TOPK_) warr[w][c0] = A0;
        if (c1 < TOPK_) warr[w][c1] = A1;
        if (c2 < TOPK_) warr[w][c2] = A2;
    }
    __syncthreads();
    // stage 2: merge 4x32 -> global top-32 via rank-count
    if (tid < 128) {
        double mine = (&warr[0][0])[tid];
        const double* wf = &warr[0][0];
        int r = 0;
#pragma unroll 8
        for (int j = 0; j < 128; j++) r += (wf[j] > mine);
        if (r < TOPK_) {
            unsigned long long u = (unsigned long long)mine;
            idx_out[(size_t)bid * TOPK_ + r] = 1023 - (int)(u & 1023ull);
        }
    }
}

// ---------------------------------------------------------------------------
// MLA absorption part 1: G[q][h][l] = sum_d qb[q][h*32+d] * up_w[h*32+d][l]
// ---------------------------------------------------------------------------
__global__ __launch_bounds__(256) void mla_g(const float* __restrict__ qb,
                                             const float* __restrict__ uw,
                                             float* __restrict__ G)
{
    int qt = blockIdx.x, h = blockIdx.y, tid = threadIdx.x;
    __shared__ float Qs[64][33];
    __shared__ float Us[32][132];
    {
        int r = tid >> 2, c0 = (tid & 3) * 8;
        const float* srcp = qb + ((size_t)(qt * 64 + r)) * E_ + h * DH + c0;
        float4 a = ((const float4*)srcp)[0];
        float4 b = ((const float4*)srcp)[1];
        Qs[r][c0 + 0] = a.x; Qs[r][c0 + 1] = a.y; Qs[r][c0 + 2] = a.z; Qs[r][c0 + 3] = a.w;
        Qs[r][c0 + 4] = b.x; Qs[r][c0 + 5] = b.y; Qs[r][c0 + 6] = b.z; Qs[r][c0 + 7] = b.w;
    }
    {
        int d = tid >> 3, l0 = (tid & 7) * 16;
        const float* srcp = uw + (size_t)(h * DH + d) * LATD + l0;
#pragma unroll
        for (int ii = 0; ii < 4; ii++) {
            float4 v = ((const float4*)srcp)[ii];
            *(float4*)&Us[d][l0 + ii * 4] = v;
        }
    }
    __syncthreads();
    int rg = tid >> 5, l = (tid & 31) * 4;
    float acc[8][4];
#pragma unroll
    for (int i = 0; i < 8; i++)
#pragma unroll
        for (int j = 0; j < 4; j++) acc[i][j] = 0.f;
    for (int d = 0; d < DH; d++) {
        float4 u = *(const float4*)&Us[d][l];
#pragma unroll
        for (int i = 0; i < 8; i++) {
            float qv = Qs[rg * 8 + i][d];
            acc[i][0] += qv * u.x; acc[i][1] += qv * u.y;
            acc[i][2] += qv * u.z; acc[i][3] += qv * u.w;
        }
    }
#pragma unroll
    for (int i = 0; i < 8; i++) {
        float4 o = {acc[i][0], acc[i][1], acc[i][2], acc[i][3]};
        *(float4*)(G + ((size_t)(qt * 64 + rg * 8 + i)) * 1024 + h * 128 + l) = o;
    }
}

// ---------------------------------------------------------------------------
// Fused sparse MLA attention per (bf, q)
// ---------------------------------------------------------------------------
__global__ __launch_bounds__(256) void mla_attn(const float* __restrict__ G,
                                                const float* __restrict__ cb,
                                                const int* __restrict__ idxb,
                                                float* __restrict__ Mo)
{
    int bid = blockIdx.x, tid = threadIdx.x;
    int bf = bid >> 10;
    __shared__ float cs[32][132];
    __shared__ float gs[8][132];
    __shared__ float swt[32][8];
    __shared__ int sidx[32];
    if (tid < 32) sidx[tid] = idxb[(size_t)bid * 32 + tid];
    {
        int flat = tid * 4, h = flat >> 7, l = flat & 127;
        float4 gv = *(const float4*)(G + (size_t)bid * 1024 + flat);
        *(float4*)&gs[h][l] = gv;
    }
    __syncthreads();
    {
        int j = tid >> 3, l0 = (tid & 7) * 16;
        const float* srcp = cb + ((size_t)(bf * SPLIT + sidx[j])) * LATD + l0;
#pragma unroll
        for (int ii = 0; ii < 4; ii++) {
            float4 vv = ((const float4*)srcp)[ii];
            *(float4*)&cs[j][l0 + ii * 4] = vv;
        }
    }
    __syncthreads();
    {
        int j = tid >> 3, h = tid & 7;
        float s = 0;
#pragma unroll
        for (int lb = 0; lb < 32; lb++) {
            float4 c4 = *(const float4*)&cs[j][lb * 4];
            float4 g4 = *(const float4*)&gs[h][lb * 4];
            s += c4.x * g4.x + c4.y * g4.y + c4.z * g4.z + c4.w * g4.w;
        }
        swt[j][h] = s * 0.17677669529663688f;
    }
    __syncthreads();
    if (tid < 8) {
        float m = swt[0][tid];
        for (int j = 1; j < 32; j++) m = fmaxf(m, swt[j][tid]);
        float sum = 0;
        for (int j = 0; j < 32; j++) { float e = expf(swt[j][tid] - m); swt[j][tid] = e; sum += e; }
        float inv = 1.0f / sum;
        for (int j = 0; j < 32; j++) swt[j][tid] *= inv;
    }
    __syncthreads();
    {
        int flat = tid * 4, h = flat >> 7, l = flat & 127;
        float4 acc = {0, 0, 0, 0};
        for (int j = 0; j < 32; j++) {
            float w = swt[j][h];
            float4 c4 = *(const float4*)&cs[j][l];
            acc.x += w * c4.x; acc.y += w * c4.y; acc.z += w * c4.z; acc.w += w * c4.w;
        }
        *(float4*)(Mo + (size_t)bid * 1024 + flat) = acc;
    }
}

// ---------------------------------------------------------------------------
// MLA absorption part 2 -> bf16 output (consumed by out-proj GEMM)
// ---------------------------------------------------------------------------
__global__ __launch_bounds__(256) void mla_out(const float* __restrict__ Mo,
                                               const float* __restrict__ uw,
                                               unsigned short* __restrict__ ob)
{
    int qt = blockIdx.x, h = blockIdx.y, tid = threadIdx.x;
    __shared__ float Ms[64][132];
    __shared__ float Us[32][129];
    {
        int r = tid >> 2, l0 = (tid & 3) * 32;
        const float* srcp = Mo + ((size_t)(qt * 64 + r)) * 1024 + h * 128 + l0;
#pragma unroll
        for (int ii = 0; ii < 8; ii++) {
            float4 v = ((const float4*)srcp)[ii];
            *(float4*)&Ms[r][l0 + ii * 4] = v;
        }
    }
    {
        int d = tid >> 3, l0 = (tid & 7) * 16;
        const float* srcp = uw + (size_t)(256 + h * DH + d) * LATD + l0;
#pragma unroll
        for (int ii = 0; ii < 4; ii++) {
            float4 v = ((const float4*)srcp)[ii];
            Us[d][l0 + ii * 4 + 0] = v.x; Us[d][l0 + ii * 4 + 1] = v.y;
            Us[d][l0 + ii * 4 + 2] = v.z; Us[d][l0 + ii * 4 + 3] = v.w;
        }
    }
    __syncthreads();
    int d = tid & 31, rg = tid >> 5;
    float acc[8] = {0, 0, 0, 0, 0, 0, 0, 0};
    for (int l = 0; l < 128; l++) {
        float u = Us[d][l];
#pragma unroll
        for (int i = 0; i < 8; i++) acc[i] += Ms[rg * 8 + i][l] * u;
    }
#pragma unroll
    for (int i = 0; i < 8; i++)
        ob[((size_t)(qt * 64 + rg * 8 + i)) * E_ + h * DH + d] = f2b(acc[i]);
}

// ---------------------------------------------------------------------------
extern "C" void kernel_launch(void* const* d_in, const int* in_sizes, int n_in,
                              void* d_out, int out_size, void* d_ws, size_t ws_size,
                              hipStream_t stream)
{
    (void)in_sizes; (void)n_in; (void)out_size; (void)ws_size;
    const float* src      = (const float*)d_in[0];
    const float* fa_in_w  = (const float*)d_in[2];
    const float* fa_in_b  = (const float*)d_in[3];
    const float* fa_out_w = (const float*)d_in[4];
    const float* fa_out_b = (const float*)d_in[5];
    const float* n1g = (const float*)d_in[6];
    const float* n1b = (const float*)d_in[7];
    const float* iqw = (const float*)d_in[8];
    const float* ikw = (const float*)d_in[9];
    const float* iow = (const float*)d_in[10];
    const float* mqw = (const float*)d_in[11];
    const float* mdw = (const float*)d_in[12];
    const float* muw = (const float*)d_in[13];
    const float* mow = (const float*)d_in[14];
    const float* n2g = (const float*)d_in[15];
    const float* n2b = (const float*)d_in[16];
    const float* l1w = (const float*)d_in[17];
    const float* l1b = (const float*)d_in[18];
    const float* l2w = (const float*)d_in[19];
    const float* l2b = (const float*)d_in[20];
    const float* n3g = (const float*)d_in[21];
    const float* n3b = (const float*)d_in[22];

    float* ws = (float*)d_ws;
    size_t off = 0;
    auto alloc = [&](size_t n) { float* p = ws + off; off += (n + 3) & ~(size_t)3; return p; };

    float* bigA = alloc((size_t)NT * 1024);   // qkv -> G -> x2 (first NT*256)
    float* Mh   = alloc((size_t)NT * 1024);   // M f32; later h1 bf16 (inside)
    float* tbuf = alloc((size_t)NT * E_);     // pre-LN buf; doubles as qb (10-11)
    float* stb  = alloc((size_t)NT * E_);     // st f32 (post-LN1, transposed)
    float* cb   = alloc((size_t)BF * SPLIT * LATD);
    unsigned short* actBF1 = (unsigned short*)alloc((size_t)NT * E_ / 2); // src16/abuf16/stb16
    unsigned short* actBF2 = (unsigned short*)alloc((size_t)NT * E_ / 2); // ob16/x216
    float* q32 = alloc((size_t)NT * 32);
    float* k32 = alloc((size_t)NT * 32);
    float* scl = alloc(128);
    int*   idxb = (int*)alloc((size_t)NT * 32);
    signed char* ki8 = (signed char*)alloc((size_t)NT * 32 / 4);
    unsigned short* w16 = (unsigned short*)alloc(950272 / 2 + 8);

    unsigned short* fa_in_w16  = w16;
    unsigned short* fa_out_w16 = fa_in_w16 + 196608;
    unsigned short* mqw16      = fa_out_w16 + 65536;
    unsigned short* mdw16      = mqw16 + 65536;
    unsigned short* mow16      = mdw16 + 32768;
    unsigned short* l1w16      = mow16 + 65536;
    unsigned short* l2w16      = l1w16 + 262144;

    float* qkv = bigA;
    float* G   = bigA;
    float* x2  = bigA;                        // LN2 out (alive after G dead)
    float* Mbuf = Mh;
    unsigned short* h116 = (unsigned short*)Mh;
    float* qb = tbuf;
    unsigned short* src16  = actBF1;
    unsigned short* abuf16 = actBF1;
    unsigned short* stb16  = actBF1;
    unsigned short* ob16   = actBF2;
    unsigned short* x216   = actBF2;

    // 0. convert weights + src to bf16
    ConvArgs ca;
    const float* segs[8] = {src, fa_in_w, fa_out_w, mqw, mdw, mow, l1w, l2w};
    unsigned short* segd[8] = {src16, fa_in_w16, fa_out_w16, mqw16, mdw16, mow16, l1w16, l2w16};
    int segn[8] = {NT * E_, 196608, 65536, 65536, 32768, 65536, 262144, 262144};
    int cum = 0;
    for (int i = 0; i < 8; i++) { ca.s[i] = segs[i]; ca.d[i] = segd[i]; cum += segn[i] / 4; ca.cum[i] = cum; }
    int totq = cum;
    convert_f2b<<<(totq + 255) / 256, 256, 0, stream>>>(ca, totq);

    dim3 blk(256);
    // 1. qkv = src @ fa_in_w^T + b
    gemm_mfma<128,128,1,0,0,0,0,0><<<dim3(6,64), blk, 0, stream>>>(src16, fa_in_w16, fa_in_b, nullptr, qkv, nullptr, NT, 768, 256);
    // 2. feature attention (S=4) -> bf16
    fa_attn<<<2048, blk, 0, stream>>>(qkv, abuf16);
    // 3. out-proj + bias + residual(src)
    gemm_mfma<128,64,1,0,1,0,0,0><<<dim3(4,64), blk, 0, stream>>>(abuf16, fa_out_w16, fa_out_b, src, tbuf, nullptr, NT, 256, 256);
    // 4. LN1, write transposed f32 + bf16
    ln_k<1,1><<<NT, dim3(64), 0, stream>>>(tbuf, n1g, n1b, stb, stb16);
    // 5. indexer projections (exact f32)
    idx_proj<<<NT, blk, 0, stream>>>(stb, iqw, ikw, q32, k32);
    // 6. scales
    idx_scales<<<96, blk, 0, stream>>>(q32, k32, scl);
    // 7. quantize k
    idx_quantk<<<(BF * SPLIT * 32) / 256, blk, 0, stream>>>(k32, scl, ki8);
    // 8. scores + top-32
    idx_score_topk<<<NT, blk, 0, stream>>>(q32, ki8, scl, iow, idxb);
    // 9. c = x_tr @ down_w^T   (train rows only)
    gemm_mfma<64,64,0,0,0,1,0,0><<<dim3(2,96), blk, 0, stream>>>(stb16, mdw16, nullptr, nullptr, cb, nullptr, BF * SPLIT, 128, 256);
    // 10. mla q projection
    gemm_mfma<128,64,0,0,0,0,0,0><<<dim3(4,64), blk, 0, stream>>>(stb16, mqw16, nullptr, nullptr, qb, nullptr, NT, 256, 256);
    // 11. G = per-head up_w(K-half)^T @ q
    mla_g<<<dim3(128,8), blk, 0, stream>>>(qb, muw, G);
    // 12. fused sparse attention -> M
    mla_attn<<<NT, blk, 0, stream>>>(G, cb, idxb, Mbuf);
    // 13. out = per-head up_w(V-half) @ M -> bf16
    mla_out<<<dim3(128,8), blk, 0, stream>>>(Mbuf, muw, ob16);
    // 14. mla out-proj + residual(stb), scatter to BRCE token rows
    gemm_mfma<128,64,0,0,1,0,1,0><<<dim3(4,64), blk, 0, stream>>>(ob16, mow16, nullptr, stb, tbuf, nullptr, NT, 256, 256);
    // 15. LN2 -> x2 f32 + bf16
    ln_k<0,1><<<NT, dim3(64), 0, stream>>>(tbuf, n2g, n2b, x2, x216);
    // 16. MLP1 + GELU -> bf16 h1
    gemm_mfma<128,128,1,1,0,0,0,1><<<dim3(8,64), blk, 0, stream>>>(x216, l1w16, l1b, nullptr, nullptr, h116, NT, MLPD, 256);
    // 17. MLP2 + bias + residual(x2)
    gemm_mfma<128,64,1,0,1,0,0,0><<<dim3(4,64), blk, 0, stream>>>(h116, l2w16, l2b, x2, tbuf, nullptr, NT, 256, MLPD);
    // 18. LN3 -> output
    ln_k<0,0><<<NT, dim3(64), 0, stream>>>(tbuf, n3g, n3b, (float*)d_out, nullptr);
}

// Round 7
// 328.302 us; speedup vs baseline: 1.4735x; 1.4422x over previous
//
#include <hip/hip_runtime.h>
#include <hip/hip_bf16.h>
#include <cmath>

#define E_ 256
#define H_ 8
#define DH 32
#define MLPD 1024
#define LATD 128
#define TOPK_ 32
#define BB 2
#define RR 1024
#define CC 4
#define NT 8192      // B*R*C tokens
#define BF 8         // B*C
#define SPLIT 768

using bf16x8 = __attribute__((ext_vector_type(8))) short;
using f32x4v = __attribute__((ext_vector_type(4))) float;

__device__ __forceinline__ unsigned short f2b(float x) {
    __hip_bfloat16 h = __float2bfloat16(x);
    return *reinterpret_cast<unsigned short*>(&h);
}

// ---------------------------------------------------------------------------
// Fused f32 -> bf16 converter for weights + src (10 segments)
// ---------------------------------------------------------------------------
struct ConvArgs {
    const float* s[10];
    unsigned short* d[10];
    int cum[10];   // cumulative quad counts (exclusive prefix ends)
};
__global__ __launch_bounds__(256) void convert_f2b(ConvArgs a, int totq)
{
    int q = blockIdx.x * 256 + threadIdx.x;
    if (q >= totq) return;
    int seg = 0;
    while (q >= a.cum[seg]) seg++;
    int lq = q - (seg ? a.cum[seg - 1] : 0);
    float4 v = ((const float4*)a.s[seg])[lq];
    ushort4 o;
    o.x = f2b(v.x); o.y = f2b(v.y); o.z = f2b(v.z); o.w = f2b(v.w);
    ((ushort4*)a.d[seg])[lq] = o;
}

// ---------------------------------------------------------------------------
// bf16 MFMA GEMM: C[M][N] = A(MxK bf16) @ W(NxK bf16)^T (+bias)(+gelu)(+res f32)
// TMxTN tile, 4 waves (2x2), frags of 16x16x32.
// AMAP: A-row gather (train rows). OMAP: st-row -> BRCE token row scatter.
// OUTBF: write bf16 (Ch) instead of f32 (Cf).
// ---------------------------------------------------------------------------
template<int TM, int TN, int BIAS, int GELU, int RES, int AMAP, int OMAP, int OUTBF>
__global__ __launch_bounds__(256) void gemm_mfma(
    const unsigned short* __restrict__ A, const unsigned short* __restrict__ W,
    const float* __restrict__ bias, const float* __restrict__ res,
    float* __restrict__ Cf, unsigned short* __restrict__ Ch,
    int M, int N, int K)
{
    __shared__ __align__(16) unsigned short As[TM * 40];
    __shared__ __align__(16) unsigned short Bs[TN * 40];
    const int tid = threadIdx.x;
    const int lane = tid & 63, wave = tid >> 6;
    const int wr = wave >> 1, wc = wave & 1;
    const int m0 = blockIdx.y * TM, n0 = blockIdx.x * TN;

    // staging coordinates
    int ra, kqa;
    if constexpr (TM == 128) { ra = tid >> 1; kqa = (tid & 1) * 16; }
    else                     { ra = tid >> 2; kqa = (tid & 3) * 8; }
    int rb, kqb;
    if constexpr (TN == 128) { rb = tid >> 1; kqb = (tid & 1) * 16; }
    else                     { rb = tid >> 2; kqb = (tid & 3) * 8; }

    int am = m0 + ra;
    size_t arow = AMAP ? ((size_t)(am / SPLIT) * RR + (am % SPLIT)) : (size_t)am;
    const unsigned short* Ap = A + arow * (size_t)K + kqa;
    const unsigned short* Bp = W + (size_t)(n0 + rb) * K + kqb;

    constexpr int FM = TM / 32, FN = TN / 32;
    f32x4v acc[FM][FN];
#pragma unroll
    for (int i = 0; i < FM; i++)
#pragma unroll
        for (int j = 0; j < FN; j++) acc[i][j] = (f32x4v){0.f, 0.f, 0.f, 0.f};

    const int kof = (lane >> 4) * 8;
    int arow_lds[FM], brow_lds[FN];
#pragma unroll
    for (int f = 0; f < FM; f++)
        arow_lds[f] = (wr * (TM / 2) + f * 16 + (lane & 15)) * 40 + kof;
#pragma unroll
    for (int f = 0; f < FN; f++)
        brow_lds[f] = (wc * (TN / 2) + f * 16 + (lane & 15)) * 40 + kof;

    for (int k0 = 0; k0 < K; k0 += 32) {
        int4 va0, va1, vb0, vb1;
        va0 = *(const int4*)(Ap + k0);
        if constexpr (TM == 128) va1 = *(const int4*)(Ap + k0 + 8);
        vb0 = *(const int4*)(Bp + k0);
        if constexpr (TN == 128) vb1 = *(const int4*)(Bp + k0 + 8);
        __syncthreads();
        *(int4*)&As[ra * 40 + kqa] = va0;
        if constexpr (TM == 128) *(int4*)&As[ra * 40 + kqa + 8] = va1;
        *(int4*)&Bs[rb * 40 + kqb] = vb0;
        if constexpr (TN == 128) *(int4*)&Bs[rb * 40 + kqb + 8] = vb1;
        __syncthreads();
        bf16x8 af[FM], bfr[FN];
#pragma unroll
        for (int f = 0; f < FM; f++) af[f] = *(const bf16x8*)&As[arow_lds[f]];
#pragma unroll
        for (int f = 0; f < FN; f++) bfr[f] = *(const bf16x8*)&Bs[brow_lds[f]];
#pragma unroll
        for (int fm = 0; fm < FM; fm++)
#pragma unroll
            for (int fn = 0; fn < FN; fn++)
                acc[fm][fn] = __builtin_amdgcn_mfma_f32_16x16x32_bf16(
                    af[fm], bfr[fn], acc[fm][fn], 0, 0, 0);
    }

#pragma unroll
    for (int fm = 0; fm < FM; fm++) {
#pragma unroll
        for (int r = 0; r < 4; r++) {
            int row = m0 + wr * (TM / 2) + fm * 16 + ((lane >> 4) << 2) + r;
            size_t orow;
            if (OMAP) {
                int bc = row >> 10, rr = row & 1023;
                int b = bc >> 2, c = bc & 3;
                orow = ((size_t)(b * RR + rr)) * CC + c;
            } else orow = (size_t)row;
#pragma unroll
            for (int fn = 0; fn < FN; fn++) {
                int col = n0 + wc * (TN / 2) + fn * 16 + (lane & 15);
                float v = acc[fm][fn][r];
                if (BIAS) v += bias[col];
                if (GELU) v = 0.5f * v * (1.0f + erff(v * 0.70710678118654752f));
                if (RES)  v += res[(size_t)row * N + col];
                if (OUTBF) Ch[orow * (size_t)N + col] = f2b(v);
                else       Cf[orow * (size_t)N + col] = v;
            }
        }
    }
}

// ---------------------------------------------------------------------------
// Feature attention: seq len 4, per (b,r) block. Vectorized float4 staging.
// ---------------------------------------------------------------------------
__global__ __launch_bounds__(256) void fa_attn(const float* __restrict__ qkv,
                                               unsigned short* __restrict__ outb)
{
    int seq = blockIdx.x, tid = threadIdx.x;
    __shared__ float sq[4][E_], sk[4][E_], sv[4][E_];
    __shared__ float ss[H_][4][4];
    __shared__ float sw[H_][4][4];
    const float4* base = (const float4*)(qkv + (size_t)seq * 3072);
#pragma unroll
    for (int p = 0; p < 3; p++) {
        int pos = tid + p * 256;            // 0..767 float4 units
        float4 v = base[pos];
        int i = pos / 192, c4 = pos % 192;
        if (c4 < 64)       *(float4*)&sq[i][c4 * 4] = v;
        else if (c4 < 128) *(float4*)&sk[i][(c4 - 64) * 4] = v;
        else               *(float4*)&sv[i][(c4 - 128) * 4] = v;
    }
    __syncthreads();
    if (tid < 128) {
        int h = tid >> 4, i = (tid >> 2) & 3, j = tid & 3;
        float s = 0;
        for (int d = 0; d < DH; d++) s += sq[i][h * DH + d] * sk[j][h * DH + d];
        ss[h][i][j] = s * 0.17677669529663688f;   // 1/sqrt(32)
    }
    __syncthreads();
    if (tid < 32) {
        int h = tid >> 2, i = tid & 3;
        float m = ss[h][i][0];
        for (int j = 1; j < 4; j++) m = fmaxf(m, ss[h][i][j]);
        float e[4], sum = 0;
        for (int j = 0; j < 4; j++) { e[j] = expf(ss[h][i][j] - m); sum += e[j]; }
        float inv = 1.0f / sum;
        for (int j = 0; j < 4; j++) sw[h][i][j] = e[j] * inv;
    }
    __syncthreads();
    int e = tid, h = e >> 5;
    for (int i = 0; i < 4; i++) {
        float o = 0;
        for (int j = 0; j < 4; j++) o += sw[h][i][j] * sv[j][e];
        outb[((size_t)(seq * 4 + i)) * E_ + e] = f2b(o);
    }
}

// ---------------------------------------------------------------------------
// LayerNorm: 4 rows per block (one row per wave). OMAP=1: token -> st row.
// WB=1: also write bf16 copy.
// ---------------------------------------------------------------------------
template<int OMAP, int WB>
__global__ __launch_bounds__(256) void ln_k(const float* __restrict__ in,
                                            const float* __restrict__ g,
                                            const float* __restrict__ bta,
                                            float* __restrict__ out,
                                            unsigned short* __restrict__ outh)
{
    int row = blockIdx.x * 4 + (threadIdx.x >> 6);
    int t = threadIdx.x & 63;
    float4 v = ((const float4*)(in + (size_t)row * E_))[t];
    float s = v.x + v.y + v.z + v.w;
#pragma unroll
    for (int o = 32; o >= 1; o >>= 1) s += __shfl_xor(s, o);
    float mean = s * (1.0f / E_);
    float dx0 = v.x - mean, dx1 = v.y - mean, dx2 = v.z - mean, dx3 = v.w - mean;
    float q = dx0 * dx0 + dx1 * dx1 + dx2 * dx2 + dx3 * dx3;
#pragma unroll
    for (int o = 32; o >= 1; o >>= 1) q += __shfl_xor(q, o);
    float inv = rsqrtf(q * (1.0f / E_) + 1e-5f);
    size_t orow;
    if (OMAP == 1) {
        int b = row >> 12, r = (row >> 2) & 1023, c = row & 3;
        orow = ((size_t)(b * CC + c)) * RR + r;
    } else orow = (size_t)row;
    int c0 = t * 4;
    float4 o;
    o.x = dx0 * inv * g[c0 + 0] + bta[c0 + 0];
    o.y = dx1 * inv * g[c0 + 1] + bta[c0 + 1];
    o.z = dx2 * inv * g[c0 + 2] + bta[c0 + 2];
    o.w = dx3 * inv * g[c0 + 3] + bta[c0 + 3];
    ((float4*)(out + orow * E_))[t] = o;
    if (WB) {
        ushort4 oh; oh.x = f2b(o.x); oh.y = f2b(o.y); oh.z = f2b(o.z); oh.w = f2b(o.w);
        ((ushort4*)(outh + orow * E_))[t] = oh;
    }
}

// ---------------------------------------------------------------------------
// Indexer scales: 96 blocks = type(0 q-train,1 q-test,2 k-train) x bf x h
// qk32 layout: [row][64], q = cols 0-31, k = cols 32-63
// ---------------------------------------------------------------------------
__global__ __launch_bounds__(256) void idx_scales(const float* __restrict__ qk32,
                                                  float* __restrict__ scl)
{
    int id = blockIdx.x;
    int type = id / 32, bf = (id % 32) >> 2, h = id & 3;
    int cofs = (type == 2) ? 32 : 0;
    int r0 = (type == 1) ? SPLIT : 0;
    int r1 = (type == 1) ? RR : SPLIT;
    float m = 0;
    for (int r = r0 + (int)threadIdx.x; r < r1; r += 256) {
        const float* p = qk32 + ((size_t)(bf * RR + r)) * 64 + cofs + h * 8;
        for (int dd = 0; dd < 8; dd++) m = fmaxf(m, fabsf(p[dd]));
    }
#pragma unroll
    for (int o = 32; o >= 1; o >>= 1) m = fmaxf(m, __shfl_xor(m, o));
    __shared__ float red[4];
    if ((threadIdx.x & 63) == 0) red[threadIdx.x >> 6] = m;
    __syncthreads();
    if (threadIdx.x == 0) {
        m = fmaxf(fmaxf(red[0], red[1]), fmaxf(red[2], red[3]));
        scl[id] = (m + 1e-6f) / 127.0f;
    }
}

// ---------------------------------------------------------------------------
// Quantize k (train rows only) to int8
// ---------------------------------------------------------------------------
__global__ __launch_bounds__(256) void idx_quantk(const float* __restrict__ qk32,
                                                  const float* __restrict__ scl,
                                                  signed char* __restrict__ ki8)
{
    int gi = blockIdx.x * 256 + threadIdx.x;     // 0 .. 8*768*32-1
    int bf = gi / (SPLIT * 32);
    int rem = gi % (SPLIT * 32);
    int r = rem >> 5, d = rem & 31, h = d >> 3;
    float ks = scl[64 + bf * 4 + h];
    float v = qk32[((size_t)(bf * RR + r)) * 64 + 32 + d];
    float qq = fminf(fmaxf(rintf(v / ks), -127.f), 127.f);
    ki8[gi] = (signed char)qq;
}

// ---------------------------------------------------------------------------
// Indexer scores + top-32 via EXACT radix-select (jax.lax.top_k tie rule).
// Key = u64 (mono_f32 << 10) | (1023-k); unique; order = (value desc, idx asc).
// Two 8-bit histogram levels on mono locate the 16-bit bucket containing
// rank 32; only keys >= threshold (typically ~40) enter exact rank-count.
// Superset proof: anything greater than a qualifying key itself qualifies,
// so within-candidate rank == global rank. Bit-identical selection.
// ---------------------------------------------------------------------------
__global__ __launch_bounds__(256) void idx_score_topk(const float* __restrict__ qk32,
                                                      const signed char* __restrict__ ki8,
                                                      const float* __restrict__ scl,
                                                      const float* __restrict__ ow,
                                                      int* __restrict__ idx_out)
{
    int bid = blockIdx.x, tid = threadIdx.x;
    int bf = bid >> 10, qr = bid & 1023;
    int sel = (qr < SPLIT) ? 0 : 32;
    __shared__ float qi[32];
    __shared__ float fac[4];
    __shared__ unsigned keyhi[SPLIT];
    __shared__ __align__(16) unsigned long long cand[SPLIT];
    __shared__ int hist[256], hist2[256], Sarr[256];
    __shared__ int bsel1, bsel2, ccnt;

    hist[tid] = 0; hist2[tid] = 0;
    if (tid == 0) ccnt = 0;
    if (tid < 32) {
        int h = tid >> 3;
        float qs = scl[sel + bf * 4 + h];
        float v = qk32[(size_t)bid * 64 + tid];
        qi[tid] = fminf(fmaxf(rintf(v / qs), -127.f), 127.f);
    }
    if (tid < 4) {
        float qs = scl[sel + bf * 4 + tid];
        float ks = scl[64 + bf * 4 + tid];
        fac[tid] = __fmul_rn(qs, ks);
    }
    __syncthreads();
    float ow0 = ow[0], ow1 = ow[1], ow2 = ow[2], ow3 = ow[3];
    for (int k = tid; k < SPLIT; k += 256) {
        const int4* kp4 = (const int4*)(ki8 + ((size_t)(bf * SPLIT + k)) * 32);
        int4 w0 = kp4[0], w1 = kp4[1];
        int wd[8] = {w0.x, w0.y, w0.z, w0.w, w1.x, w1.y, w1.z, w1.w};
        float owv[4] = {ow0, ow1, ow2, ow3};
        float r = 0;
#pragma unroll
        for (int h = 0; h < 4; h++) {
            float dot = 0.f;
#pragma unroll
            for (int b = 0; b < 2; b++) {
                unsigned int w = (unsigned int)wd[h * 2 + b];
#pragma unroll
                for (int by = 0; by < 4; by++) {
                    float kv = (float)((signed char)(w >> (8 * by)));
                    dot = fmaf(qi[h * 8 + b * 4 + by], kv, dot);
                }
            }
            float sc = fmaxf(__fmul_rn(dot, fac[h]), 0.f);
            r = __fadd_rn(r, __fmul_rn(sc, owv[h]));
        }
        unsigned int bitsv = __float_as_uint(r);
        unsigned int mono = (bitsv & 0x80000000u) ? ~bitsv : (bitsv | 0x80000000u);
        if (mono == 0x7FFFFFFFu) mono = 0x80000000u;   // canonicalize -0 == +0
        keyhi[k] = mono;
        atomicAdd(&hist[mono >> 24], 1);
    }
    __syncthreads();
    // level-1 suffix counts S(b) = # keys with hibyte > b  (wave 0)
    if (tid < 64) {
        int4 h4 = *(const int4*)&hist[tid * 4];
        int local = h4.x + h4.y + h4.z + h4.w;
        int s = local;
#pragma unroll
        for (int o = 1; o < 64; o <<= 1) {
            int x = __shfl_down(s, o);
            if (tid + o < 64) s += x;
        }
        int sufE = s - local;
        Sarr[tid * 4 + 0] = sufE + h4.y + h4.z + h4.w;
        Sarr[tid * 4 + 1] = sufE + h4.z + h4.w;
        Sarr[tid * 4 + 2] = sufE + h4.w;
        Sarr[tid * 4 + 3] = sufE;
    }
    __syncthreads();
    if (Sarr[tid] < TOPK_ && Sarr[tid] + hist[tid] >= TOPK_) bsel1 = tid;
    __syncthreads();
    const int b1 = bsel1;
    const int S1 = Sarr[b1];
    // level-2 histogram among keys with hibyte == b1
    for (int k = tid; k < SPLIT; k += 256) {
        unsigned mono = keyhi[k];
        if ((int)(mono >> 24) == b1) atomicAdd(&hist2[(mono >> 16) & 255], 1);
    }
    __syncthreads();
    if (tid < 64) {
        int4 h4 = *(const int4*)&hist2[tid * 4];
        int local = h4.x + h4.y + h4.z + h4.w;
        int s = local;
#pragma unroll
        for (int o = 1; o < 64; o <<= 1) {
            int x = __shfl_down(s, o);
            if (tid + o < 64) s += x;
        }
        int sufE = s - local;
        Sarr[tid * 4 + 0] = sufE + h4.y + h4.z + h4.w;
        Sarr[tid * 4 + 1] = sufE + h4.z + h4.w;
        Sarr[tid * 4 + 2] = sufE + h4.w;
        Sarr[tid * 4 + 3] = sufE;
    }
    __syncthreads();
    if (S1 + Sarr[tid] < TOPK_ && S1 + Sarr[tid] + hist2[tid] >= TOPK_) bsel2 = tid;
    __syncthreads();
    const int b2 = bsel2;
    // collect candidates: (hi > b1) || (hi == b1 && mid >= b2)
    for (int k = tid; k < SPLIT; k += 256) {
        unsigned mono = keyhi[k];
        int hi = mono >> 24, mid = (mono >> 16) & 255;
        if (hi > b1 || (hi == b1 && mid >= b2)) {
            int s = atomicAdd(&ccnt, 1);
            cand[s] = ((unsigned long long)mono << 10) | (unsigned)(1023 - k);
        }
    }
    __syncthreads();
    const int n = ccnt;
    for (int ci = tid; ci < n; ci += 256) {
        unsigned long long mine = cand[ci];
        int r = 0;
        for (int j = 0; j < n; j++) r += (cand[j] > mine);
        if (r < TOPK_)
            idx_out[(size_t)bid * TOPK_ + r] = 1023 - (int)(mine & 1023ull);
    }
}

// ---------------------------------------------------------------------------
// MLA absorption part 1: G[q][h][l] = sum_d qb[q][h*32+d] * up_w[h*32+d][l]
// ---------------------------------------------------------------------------
__global__ __launch_bounds__(256) void mla_g(const float* __restrict__ qb,
                                             const float* __restrict__ uw,
                                             float* __restrict__ G)
{
    int qt = blockIdx.x, h = blockIdx.y, tid = threadIdx.x;
    __shared__ float Qs[64][33];
    __shared__ float Us[32][132];
    {
        int r = tid >> 2, c0 = (tid & 3) * 8;
        const float* srcp = qb + ((size_t)(qt * 64 + r)) * E_ + h * DH + c0;
        float4 a = ((const float4*)srcp)[0];
        float4 b = ((const float4*)srcp)[1];
        Qs[r][c0 + 0] = a.x; Qs[r][c0 + 1] = a.y; Qs[r][c0 + 2] = a.z; Qs[r][c0 + 3] = a.w;
        Qs[r][c0 + 4] = b.x; Qs[r][c0 + 5] = b.y; Qs[r][c0 + 6] = b.z; Qs[r][c0 + 7] = b.w;
    }
    {
        int d = tid >> 3, l0 = (tid & 7) * 16;
        const float* srcp = uw + (size_t)(h * DH + d) * LATD + l0;
#pragma unroll
        for (int ii = 0; ii < 4; ii++) {
            float4 v = ((const float4*)srcp)[ii];
            *(float4*)&Us[d][l0 + ii * 4] = v;
        }
    }
    __syncthreads();
    int rg = tid >> 5, l = (tid & 31) * 4;
    float acc[8][4];
#pragma unroll
    for (int i = 0; i < 8; i++)
#pragma unroll
        for (int j = 0; j < 4; j++) acc[i][j] = 0.f;
    for (int d = 0; d < DH; d++) {
        float4 u = *(const float4*)&Us[d][l];
#pragma unroll
        for (int i = 0; i < 8; i++) {
            float qv = Qs[rg * 8 + i][d];
            acc[i][0] += qv * u.x; acc[i][1] += qv * u.y;
            acc[i][2] += qv * u.z; acc[i][3] += qv * u.w;
        }
    }
#pragma unroll
    for (int i = 0; i < 8; i++) {
        float4 o = {acc[i][0], acc[i][1], acc[i][2], acc[i][3]};
        *(float4*)(G + ((size_t)(qt * 64 + rg * 8 + i)) * 1024 + h * 128 + l) = o;
    }
}

// ---------------------------------------------------------------------------
// Fused sparse MLA attention per (bf, q)
// ---------------------------------------------------------------------------
__global__ __launch_bounds__(256) void mla_attn(const float* __restrict__ G,
                                                const float* __restrict__ cb,
                                                const int* __restrict__ idxb,
                                                float* __restrict__ Mo)
{
    int bid = blockIdx.x, tid = threadIdx.x;
    int bf = bid >> 10;
    __shared__ float cs[32][132];
    __shared__ float gs[8][132];
    __shared__ float swt[32][8];
    __shared__ int sidx[32];
    if (tid < 32) sidx[tid] = idxb[(size_t)bid * 32 + tid];
    {
        int flat = tid * 4, h = flat >> 7, l = flat & 127;
        float4 gv = *(const float4*)(G + (size_t)bid * 1024 + flat);
        *(float4*)&gs[h][l] = gv;
    }
    __syncthreads();
    {
        int j = tid >> 3, l0 = (tid & 7) * 16;
        const float* srcp = cb + ((size_t)(bf * SPLIT + sidx[j])) * LATD + l0;
#pragma unroll
        for (int ii = 0; ii < 4; ii++) {
            float4 vv = ((const float4*)srcp)[ii];
            *(float4*)&cs[j][l0 + ii * 4] = vv;
        }
    }
    __syncthreads();
    {
        int j = tid >> 3, h = tid & 7;
        float s = 0;
#pragma unroll
        for (int lb = 0; lb < 32; lb++) {
            float4 c4 = *(const float4*)&cs[j][lb * 4];
            float4 g4 = *(const float4*)&gs[h][lb * 4];
            s += c4.x * g4.x + c4.y * g4.y + c4.z * g4.z + c4.w * g4.w;
        }
        swt[j][h] = s * 0.17677669529663688f;
    }
    __syncthreads();
    if (tid < 8) {
        float m = swt[0][tid];
        for (int j = 1; j < 32; j++) m = fmaxf(m, swt[j][tid]);
        float sum = 0;
        for (int j = 0; j < 32; j++) { float e = expf(swt[j][tid] - m); swt[j][tid] = e; sum += e; }
        float inv = 1.0f / sum;
        for (int j = 0; j < 32; j++) swt[j][tid] *= inv;
    }
    __syncthreads();
    {
        int flat = tid * 4, h = flat >> 7, l = flat & 127;
        float4 acc = {0, 0, 0, 0};
        for (int j = 0; j < 32; j++) {
            float w = swt[j][h];
            float4 c4 = *(const float4*)&cs[j][l];
            acc.x += w * c4.x; acc.y += w * c4.y; acc.z += w * c4.z; acc.w += w * c4.w;
        }
        *(float4*)(Mo + (size_t)bid * 1024 + flat) = acc;
    }
}

// ---------------------------------------------------------------------------
// MLA absorption part 2 -> bf16 output (consumed by out-proj GEMM)
// ---------------------------------------------------------------------------
__global__ __launch_bounds__(256) void mla_out(const float* __restrict__ Mo,
                                               const float* __restrict__ uw,
                                               unsigned short* __restrict__ ob)
{
    int qt = blockIdx.x, h = blockIdx.y, tid = threadIdx.x;
    __shared__ float Ms[64][132];
    __shared__ float Us[32][129];
    {
        int r = tid >> 2, l0 = (tid & 3) * 32;
        const float* srcp = Mo + ((size_t)(qt * 64 + r)) * 1024 + h * 128 + l0;
#pragma unroll
        for (int ii = 0; ii < 8; ii++) {
            float4 v = ((const float4*)srcp)[ii];
            *(float4*)&Ms[r][l0 + ii * 4] = v;
        }
    }
    {
        int d = tid >> 3, l0 = (tid & 7) * 16;
        const float* srcp = uw + (size_t)(256 + h * DH + d) * LATD + l0;
#pragma unroll
        for (int ii = 0; ii < 4; ii++) {
            float4 v = ((const float4*)srcp)[ii];
            Us[d][l0 + ii * 4 + 0] = v.x; Us[d][l0 + ii * 4 + 1] = v.y;
            Us[d][l0 + ii * 4 + 2] = v.z; Us[d][l0 + ii * 4 + 3] = v.w;
        }
    }
    __syncthreads();
    int d = tid & 31, rg = tid >> 5;
    float acc[8] = {0, 0, 0, 0, 0, 0, 0, 0};
    for (int l = 0; l < 128; l++) {
        float u = Us[d][l];
#pragma unroll
        for (int i = 0; i < 8; i++) acc[i] += Ms[rg * 8 + i][l] * u;
    }
#pragma unroll
    for (int i = 0; i < 8; i++)
        ob[((size_t)(qt * 64 + rg * 8 + i)) * E_ + h * DH + d] = f2b(acc[i]);
}

// ---------------------------------------------------------------------------
extern "C" void kernel_launch(void* const* d_in, const int* in_sizes, int n_in,
                              void* d_out, int out_size, void* d_ws, size_t ws_size,
                              hipStream_t stream)
{
    (void)in_sizes; (void)n_in; (void)out_size; (void)ws_size;
    const float* src      = (const float*)d_in[0];
    const float* fa_in_w  = (const float*)d_in[2];
    const float* fa_in_b  = (const float*)d_in[3];
    const float* fa_out_w = (const float*)d_in[4];
    const float* fa_out_b = (const float*)d_in[5];
    const float* n1g = (const float*)d_in[6];
    const float* n1b = (const float*)d_in[7];
    const float* iqw = (const float*)d_in[8];
    const float* ikw = (const float*)d_in[9];
    const float* iow = (const float*)d_in[10];
    const float* mqw = (const float*)d_in[11];
    const float* mdw = (const float*)d_in[12];
    const float* muw = (const float*)d_in[13];
    const float* mow = (const float*)d_in[14];
    const float* n2g = (const float*)d_in[15];
    const float* n2b = (const float*)d_in[16];
    const float* l1w = (const float*)d_in[17];
    const float* l1b = (const float*)d_in[18];
    const float* l2w = (const float*)d_in[19];
    const float* l2b = (const float*)d_in[20];
    const float* n3g = (const float*)d_in[21];
    const float* n3b = (const float*)d_in[22];

    float* ws = (float*)d_ws;
    size_t off = 0;
    auto alloc = [&](size_t n) { float* p = ws + off; off += (n + 3) & ~(size_t)3; return p; };

    float* bigA = alloc((size_t)NT * 1024);   // qkv -> G -> x2 (first NT*256)
    float* Mh   = alloc((size_t)NT * 1024);   // M f32; later h1 bf16 (inside)
    float* tbuf = alloc((size_t)NT * E_);     // pre-LN buf; doubles as qb (10-11)
    float* stb  = alloc((size_t)NT * E_);     // st f32 (post-LN1, transposed)
    float* cb   = alloc((size_t)BF * SPLIT * LATD);
    unsigned short* actBF1 = (unsigned short*)alloc((size_t)NT * E_ / 2); // src16/abuf16/stb16
    unsigned short* actBF2 = (unsigned short*)alloc((size_t)NT * E_ / 2); // ob16/x216
    float* qk32 = alloc((size_t)NT * 64);     // [row][64]: q cols 0-31, k cols 32-63
    float* scl = alloc(128);
    int*   idxb = (int*)alloc((size_t)NT * 32);
    signed char* ki8 = (signed char*)alloc((size_t)NT * 32 / 4);
    unsigned short* w16 = (unsigned short*)alloc(950272 / 2 + 8);
    unsigned short* wqk16 = (unsigned short*)alloc(16384 / 2 + 8);   // [iqw;ikw] 64x256

    unsigned short* fa_in_w16  = w16;
    unsigned short* fa_out_w16 = fa_in_w16 + 196608;
    unsigned short* mqw16      = fa_out_w16 + 65536;
    unsigned short* mdw16      = mqw16 + 65536;
    unsigned short* mow16      = mdw16 + 32768;
    unsigned short* l1w16      = mow16 + 65536;
    unsigned short* l2w16      = l1w16 + 262144;

    float* qkv = bigA;
    float* G   = bigA;
    float* x2  = bigA;                        // LN2 out (alive after G dead)
    float* Mbuf = Mh;
    unsigned short* h116 = (unsigned short*)Mh;
    float* qb = tbuf;
    unsigned short* src16  = actBF1;
    unsigned short* abuf16 = actBF1;
    unsigned short* stb16  = actBF1;
    unsigned short* ob16   = actBF2;
    unsigned short* x216   = actBF2;

    // 0. convert weights + src to bf16
    ConvArgs ca;
    const float* segs[10] = {src, fa_in_w, fa_out_w, mqw, mdw, mow, l1w, l2w, iqw, ikw};
    unsigned short* segd[10] = {src16, fa_in_w16, fa_out_w16, mqw16, mdw16, mow16, l1w16, l2w16,
                                wqk16, wqk16 + 8192};
    int segn[10] = {NT * E_, 196608, 65536, 65536, 32768, 65536, 262144, 262144, 8192, 8192};
    int cum = 0;
    for (int i = 0; i < 10; i++) { ca.s[i] = segs[i]; ca.d[i] = segd[i]; cum += segn[i] / 4; ca.cum[i] = cum; }
    int totq = cum;
    convert_f2b<<<(totq + 255) / 256, 256, 0, stream>>>(ca, totq);

    dim3 blk(256);
    // 1. qkv = src @ fa_in_w^T + b
    gemm_mfma<128,128,1,0,0,0,0,0><<<dim3(6,64), blk, 0, stream>>>(src16, fa_in_w16, fa_in_b, nullptr, qkv, nullptr, NT, 768, 256);
    // 2. feature attention (S=4) -> bf16
    fa_attn<<<2048, blk, 0, stream>>>(qkv, abuf16);
    // 3. out-proj + bias + residual(src)
    gemm_mfma<128,64,1,0,1,0,0,0><<<dim3(4,64), blk, 0, stream>>>(abuf16, fa_out_w16, fa_out_b, src, tbuf, nullptr, NT, 256, 256);
    // 4. LN1, write transposed f32 + bf16
    ln_k<1,1><<<NT/4, blk, 0, stream>>>(tbuf, n1g, n1b, stb, stb16);
    // 5. indexer projections as MFMA GEMM -> qk32 [row][64]
    gemm_mfma<128,64,0,0,0,0,0,0><<<dim3(1,64), blk, 0, stream>>>(stb16, wqk16, nullptr, nullptr, qk32, nullptr, NT, 64, 256);
    // 6. scales
    idx_scales<<<96, blk, 0, stream>>>(qk32, scl);
    // 7. quantize k
    idx_quantk<<<(BF * SPLIT * 32) / 256, blk, 0, stream>>>(qk32, scl, ki8);
    // 8. scores + top-32 (radix-select)
    idx_score_topk<<<NT, blk, 0, stream>>>(qk32, ki8, scl, iow, idxb);
    // 9. c = x_tr @ down_w^T   (train rows only)
    gemm_mfma<64,64,0,0,0,1,0,0><<<dim3(2,96), blk, 0, stream>>>(stb16, mdw16, nullptr, nullptr, cb, nullptr, BF * SPLIT, 128, 256);
    // 10. mla q projection
    gemm_mfma<128,64,0,0,0,0,0,0><<<dim3(4,64), blk, 0, stream>>>(stb16, mqw16, nullptr, nullptr, qb, nullptr, NT, 256, 256);
    // 11. G = per-head up_w(K-half)^T @ q
    mla_g<<<dim3(128,8), blk, 0, stream>>>(qb, muw, G);
    // 12. fused sparse attention -> M
    mla_attn<<<NT, blk, 0, stream>>>(G, cb, idxb, Mbuf);
    // 13. out = per-head up_w(V-half) @ M -> bf16
    mla_out<<<dim3(128,8), blk, 0, stream>>>(Mbuf, muw, ob16);
    // 14. mla out-proj + residual(stb), scatter to BRCE token rows
    gemm_mfma<128,64,0,0,1,0,1,0><<<dim3(4,64), blk, 0, stream>>>(ob16, mow16, nullptr, stb, tbuf, nullptr, NT, 256, 256);
    // 15. LN2 -> x2 f32 + bf16
    ln_k<0,1><<<NT/4, blk, 0, stream>>>(tbuf, n2g, n2b, x2, x216);
    // 16. MLP1 + GELU -> bf16 h1
    gemm_mfma<128,128,1,1,0,0,0,1><<<dim3(8,64), blk, 0, stream>>>(x216, l1w16, l1b, nullptr, nullptr, h116, NT, MLPD, 256);
    // 17. MLP2 + bias + residual(x2)
    gemm_mfma<128,64,1,0,1,0,0,0><<<dim3(4,64), blk, 0, stream>>>(h116, l2w16, l2b, x2, tbuf, nullptr, NT, 256, MLPD);
    // 18. LN3 -> output
    ln_k<0,0><<<NT/4, blk, 0, stream>>>(tbuf, n3g, n3b, (float*)d_out, nullptr);
}

// Round 8
// 309.558 us; speedup vs baseline: 1.5628x; 1.0606x over previous
//
#include <hip/hip_runtime.h>
#include <hip/hip_bf16.h>
#include <cmath>

#define E_ 256
#define H_ 8
#define DH 32
#define MLPD 1024
#define LATD 128
#define TOPK_ 32
#define BB 2
#define RR 1024
#define CC 4
#define NT 8192      // B*R*C tokens
#define BF 8         // B*C
#define SPLIT 768

using bf16x8 = __attribute__((ext_vector_type(8))) short;
using f32x4v = __attribute__((ext_vector_type(4))) float;

__device__ __forceinline__ unsigned short f2b(float x) {
    __hip_bfloat16 h = __float2bfloat16(x);
    return *reinterpret_cast<unsigned short*>(&h);
}
__device__ __forceinline__ float b2f(unsigned short u) {
    return __uint_as_float(((unsigned)u) << 16);
}

// ---------------------------------------------------------------------------
// Fused f32 -> bf16 converter for weights + src (10 segments)
// ---------------------------------------------------------------------------
struct ConvArgs {
    const float* s[10];
    unsigned short* d[10];
    int cum[10];   // cumulative quad counts (exclusive prefix ends)
};
__global__ __launch_bounds__(256) void convert_f2b(ConvArgs a, int totq)
{
    int q = blockIdx.x * 256 + threadIdx.x;
    if (q >= totq) return;
    int seg = 0;
    while (q >= a.cum[seg]) seg++;
    int lq = q - (seg ? a.cum[seg - 1] : 0);
    float4 v = ((const float4*)a.s[seg])[lq];
    ushort4 o;
    o.x = f2b(v.x); o.y = f2b(v.y); o.z = f2b(v.z); o.w = f2b(v.w);
    ((ushort4*)a.d[seg])[lq] = o;
}

// ---------------------------------------------------------------------------
// bf16 MFMA GEMM: C[M][N] = A(MxK bf16) @ W(NxK bf16)^T (+bias)(+gelu)(+res f32)
// TMxTN tile, 4 waves (2x2), frags of 16x16x32.
// ---------------------------------------------------------------------------
template<int TM, int TN, int BIAS, int GELU, int RES, int AMAP, int OMAP, int OUTBF>
__global__ __launch_bounds__(256) void gemm_mfma(
    const unsigned short* __restrict__ A, const unsigned short* __restrict__ W,
    const float* __restrict__ bias, const float* __restrict__ res,
    float* __restrict__ Cf, unsigned short* __restrict__ Ch,
    int M, int N, int K)
{
    __shared__ __align__(16) unsigned short As[TM * 40];
    __shared__ __align__(16) unsigned short Bs[TN * 40];
    const int tid = threadIdx.x;
    const int lane = tid & 63, wave = tid >> 6;
    const int wr = wave >> 1, wc = wave & 1;
    const int m0 = blockIdx.y * TM, n0 = blockIdx.x * TN;

    int ra, kqa;
    if constexpr (TM == 128) { ra = tid >> 1; kqa = (tid & 1) * 16; }
    else                     { ra = tid >> 2; kqa = (tid & 3) * 8; }
    int rb, kqb;
    if constexpr (TN == 128) { rb = tid >> 1; kqb = (tid & 1) * 16; }
    else                     { rb = tid >> 2; kqb = (tid & 3) * 8; }

    int am = m0 + ra;
    size_t arow = AMAP ? ((size_t)(am / SPLIT) * RR + (am % SPLIT)) : (size_t)am;
    const unsigned short* Ap = A + arow * (size_t)K + kqa;
    const unsigned short* Bp = W + (size_t)(n0 + rb) * K + kqb;

    constexpr int FM = TM / 32, FN = TN / 32;
    f32x4v acc[FM][FN];
#pragma unroll
    for (int i = 0; i < FM; i++)
#pragma unroll
        for (int j = 0; j < FN; j++) acc[i][j] = (f32x4v){0.f, 0.f, 0.f, 0.f};

    const int kof = (lane >> 4) * 8;
    int arow_lds[FM], brow_lds[FN];
#pragma unroll
    for (int f = 0; f < FM; f++)
        arow_lds[f] = (wr * (TM / 2) + f * 16 + (lane & 15)) * 40 + kof;
#pragma unroll
    for (int f = 0; f < FN; f++)
        brow_lds[f] = (wc * (TN / 2) + f * 16 + (lane & 15)) * 40 + kof;

    for (int k0 = 0; k0 < K; k0 += 32) {
        int4 va0, va1, vb0, vb1;
        va0 = *(const int4*)(Ap + k0);
        if constexpr (TM == 128) va1 = *(const int4*)(Ap + k0 + 8);
        vb0 = *(const int4*)(Bp + k0);
        if constexpr (TN == 128) vb1 = *(const int4*)(Bp + k0 + 8);
        __syncthreads();
        *(int4*)&As[ra * 40 + kqa] = va0;
        if constexpr (TM == 128) *(int4*)&As[ra * 40 + kqa + 8] = va1;
        *(int4*)&Bs[rb * 40 + kqb] = vb0;
        if constexpr (TN == 128) *(int4*)&Bs[rb * 40 + kqb + 8] = vb1;
        __syncthreads();
        bf16x8 af[FM], bfr[FN];
#pragma unroll
        for (int f = 0; f < FM; f++) af[f] = *(const bf16x8*)&As[arow_lds[f]];
#pragma unroll
        for (int f = 0; f < FN; f++) bfr[f] = *(const bf16x8*)&Bs[brow_lds[f]];
#pragma unroll
        for (int fm = 0; fm < FM; fm++)
#pragma unroll
            for (int fn = 0; fn < FN; fn++)
                acc[fm][fn] = __builtin_amdgcn_mfma_f32_16x16x32_bf16(
                    af[fm], bfr[fn], acc[fm][fn], 0, 0, 0);
    }

#pragma unroll
    for (int fm = 0; fm < FM; fm++) {
#pragma unroll
        for (int r = 0; r < 4; r++) {
            int row = m0 + wr * (TM / 2) + fm * 16 + ((lane >> 4) << 2) + r;
            size_t orow;
            if (OMAP) {
                int bc = row >> 10, rr = row & 1023;
                int b = bc >> 2, c = bc & 3;
                orow = ((size_t)(b * RR + rr)) * CC + c;
            } else orow = (size_t)row;
#pragma unroll
            for (int fn = 0; fn < FN; fn++) {
                int col = n0 + wc * (TN / 2) + fn * 16 + (lane & 15);
                float v = acc[fm][fn][r];
                if (BIAS) v += bias[col];
                if (GELU) v = 0.5f * v * (1.0f + erff(v * 0.70710678118654752f));
                if (RES)  v += res[(size_t)row * N + col];
                if (OUTBF) Ch[orow * (size_t)N + col] = f2b(v);
                else       Cf[orow * (size_t)N + col] = v;
            }
        }
    }
}

// ---------------------------------------------------------------------------
// Feature attention: seq len 4, per (b,r) block. Vectorized float4 staging.
// ---------------------------------------------------------------------------
__global__ __launch_bounds__(256) void fa_attn(const float* __restrict__ qkv,
                                               unsigned short* __restrict__ outb)
{
    int seq = blockIdx.x, tid = threadIdx.x;
    __shared__ float sq[4][E_], sk[4][E_], sv[4][E_];
    __shared__ float ss[H_][4][4];
    __shared__ float sw[H_][4][4];
    const float4* base = (const float4*)(qkv + (size_t)seq * 3072);
#pragma unroll
    for (int p = 0; p < 3; p++) {
        int pos = tid + p * 256;            // 0..767 float4 units
        float4 v = base[pos];
        int i = pos / 192, c4 = pos % 192;
        if (c4 < 64)       *(float4*)&sq[i][c4 * 4] = v;
        else if (c4 < 128) *(float4*)&sk[i][(c4 - 64) * 4] = v;
        else               *(float4*)&sv[i][(c4 - 128) * 4] = v;
    }
    __syncthreads();
    if (tid < 128) {
        int h = tid >> 4, i = (tid >> 2) & 3, j = tid & 3;
        float s = 0;
        for (int d = 0; d < DH; d++) s += sq[i][h * DH + d] * sk[j][h * DH + d];
        ss[h][i][j] = s * 0.17677669529663688f;   // 1/sqrt(32)
    }
    __syncthreads();
    if (tid < 32) {
        int h = tid >> 2, i = tid & 3;
        float m = ss[h][i][0];
        for (int j = 1; j < 4; j++) m = fmaxf(m, ss[h][i][j]);
        float e[4], sum = 0;
        for (int j = 0; j < 4; j++) { e[j] = expf(ss[h][i][j] - m); sum += e[j]; }
        float inv = 1.0f / sum;
        for (int j = 0; j < 4; j++) sw[h][i][j] = e[j] * inv;
    }
    __syncthreads();
    int e = tid, h = e >> 5;
    for (int i = 0; i < 4; i++) {
        float o = 0;
        for (int j = 0; j < 4; j++) o += sw[h][i][j] * sv[j][e];
        outb[((size_t)(seq * 4 + i)) * E_ + e] = f2b(o);
    }
}

// ---------------------------------------------------------------------------
// LayerNorm: 4 rows per block (one row per wave). OMAP=1: token -> st row.
// ---------------------------------------------------------------------------
template<int OMAP, int WB>
__global__ __launch_bounds__(256) void ln_k(const float* __restrict__ in,
                                            const float* __restrict__ g,
                                            const float* __restrict__ bta,
                                            float* __restrict__ out,
                                            unsigned short* __restrict__ outh)
{
    int row = blockIdx.x * 4 + (threadIdx.x >> 6);
    int t = threadIdx.x & 63;
    float4 v = ((const float4*)(in + (size_t)row * E_))[t];
    float s = v.x + v.y + v.z + v.w;
#pragma unroll
    for (int o = 32; o >= 1; o >>= 1) s += __shfl_xor(s, o);
    float mean = s * (1.0f / E_);
    float dx0 = v.x - mean, dx1 = v.y - mean, dx2 = v.z - mean, dx3 = v.w - mean;
    float q = dx0 * dx0 + dx1 * dx1 + dx2 * dx2 + dx3 * dx3;
#pragma unroll
    for (int o = 32; o >= 1; o >>= 1) q += __shfl_xor(q, o);
    float inv = rsqrtf(q * (1.0f / E_) + 1e-5f);
    size_t orow;
    if (OMAP == 1) {
        int b = row >> 12, r = (row >> 2) & 1023, c = row & 3;
        orow = ((size_t)(b * CC + c)) * RR + r;
    } else orow = (size_t)row;
    int c0 = t * 4;
    float4 o;
    o.x = dx0 * inv * g[c0 + 0] + bta[c0 + 0];
    o.y = dx1 * inv * g[c0 + 1] + bta[c0 + 1];
    o.z = dx2 * inv * g[c0 + 2] + bta[c0 + 2];
    o.w = dx3 * inv * g[c0 + 3] + bta[c0 + 3];
    ((float4*)(out + orow * E_))[t] = o;
    if (WB) {
        ushort4 oh; oh.x = f2b(o.x); oh.y = f2b(o.y); oh.z = f2b(o.z); oh.w = f2b(o.w);
        ((ushort4*)(outh + orow * E_))[t] = oh;
    }
}

// ---------------------------------------------------------------------------
// Indexer scales
// ---------------------------------------------------------------------------
__global__ __launch_bounds__(256) void idx_scales(const float* __restrict__ qk32,
                                                  float* __restrict__ scl)
{
    int id = blockIdx.x;
    int type = id / 32, bf = (id % 32) >> 2, h = id & 3;
    int cofs = (type == 2) ? 32 : 0;
    int r0 = (type == 1) ? SPLIT : 0;
    int r1 = (type == 1) ? RR : SPLIT;
    float m = 0;
    for (int r = r0 + (int)threadIdx.x; r < r1; r += 256) {
        const float* p = qk32 + ((size_t)(bf * RR + r)) * 64 + cofs + h * 8;
        for (int dd = 0; dd < 8; dd++) m = fmaxf(m, fabsf(p[dd]));
    }
#pragma unroll
    for (int o = 32; o >= 1; o >>= 1) m = fmaxf(m, __shfl_xor(m, o));
    __shared__ float red[4];
    if ((threadIdx.x & 63) == 0) red[threadIdx.x >> 6] = m;
    __syncthreads();
    if (threadIdx.x == 0) {
        m = fmaxf(fmaxf(red[0], red[1]), fmaxf(red[2], red[3]));
        scl[id] = (m + 1e-6f) / 127.0f;
    }
}

// ---------------------------------------------------------------------------
// Quantize k (train rows only) to int8
// ---------------------------------------------------------------------------
__global__ __launch_bounds__(256) void idx_quantk(const float* __restrict__ qk32,
                                                  const float* __restrict__ scl,
                                                  signed char* __restrict__ ki8)
{
    int gi = blockIdx.x * 256 + threadIdx.x;     // 0 .. 8*768*32-1
    int bf = gi / (SPLIT * 32);
    int rem = gi % (SPLIT * 32);
    int r = rem >> 5, d = rem & 31, h = d >> 3;
    float ks = scl[64 + bf * 4 + h];
    float v = qk32[((size_t)(bf * RR + r)) * 64 + 32 + d];
    float qq = fminf(fmaxf(rintf(v / ks), -127.f), 127.f);
    ki8[gi] = (signed char)qq;
}

// ---------------------------------------------------------------------------
// Indexer scores + top-32 via EXACT radix-select (jax.lax.top_k tie rule).
// ---------------------------------------------------------------------------
__global__ __launch_bounds__(256) void idx_score_topk(const float* __restrict__ qk32,
                                                      const signed char* __restrict__ ki8,
                                                      const float* __restrict__ scl,
                                                      const float* __restrict__ ow,
                                                      int* __restrict__ idx_out)
{
    int bid = blockIdx.x, tid = threadIdx.x;
    int bf = bid >> 10, qr = bid & 1023;
    int sel = (qr < SPLIT) ? 0 : 32;
    __shared__ float qi[32];
    __shared__ float fac[4];
    __shared__ unsigned keyhi[SPLIT];
    __shared__ __align__(16) unsigned long long cand[SPLIT];
    __shared__ int hist[256], hist2[256], Sarr[256];
    __shared__ int bsel1, bsel2, ccnt;

    hist[tid] = 0; hist2[tid] = 0;
    if (tid == 0) ccnt = 0;
    if (tid < 32) {
        int h = tid >> 3;
        float qs = scl[sel + bf * 4 + h];
        float v = qk32[(size_t)bid * 64 + tid];
        qi[tid] = fminf(fmaxf(rintf(v / qs), -127.f), 127.f);
    }
    if (tid < 4) {
        float qs = scl[sel + bf * 4 + tid];
        float ks = scl[64 + bf * 4 + tid];
        fac[tid] = __fmul_rn(qs, ks);
    }
    __syncthreads();
    float ow0 = ow[0], ow1 = ow[1], ow2 = ow[2], ow3 = ow[3];
    for (int k = tid; k < SPLIT; k += 256) {
        const int4* kp4 = (const int4*)(ki8 + ((size_t)(bf * SPLIT + k)) * 32);
        int4 w0 = kp4[0], w1 = kp4[1];
        int wd[8] = {w0.x, w0.y, w0.z, w0.w, w1.x, w1.y, w1.z, w1.w};
        float owv[4] = {ow0, ow1, ow2, ow3};
        float r = 0;
#pragma unroll
        for (int h = 0; h < 4; h++) {
            float dot = 0.f;
#pragma unroll
            for (int b = 0; b < 2; b++) {
                unsigned int w = (unsigned int)wd[h * 2 + b];
#pragma unroll
                for (int by = 0; by < 4; by++) {
                    float kv = (float)((signed char)(w >> (8 * by)));
                    dot = fmaf(qi[h * 8 + b * 4 + by], kv, dot);
                }
            }
            float sc = fmaxf(__fmul_rn(dot, fac[h]), 0.f);
            r = __fadd_rn(r, __fmul_rn(sc, owv[h]));
        }
        unsigned int bitsv = __float_as_uint(r);
        unsigned int mono = (bitsv & 0x80000000u) ? ~bitsv : (bitsv | 0x80000000u);
        if (mono == 0x7FFFFFFFu) mono = 0x80000000u;   // canonicalize -0 == +0
        keyhi[k] = mono;
        atomicAdd(&hist[mono >> 24], 1);
    }
    __syncthreads();
    if (tid < 64) {
        int4 h4 = *(const int4*)&hist[tid * 4];
        int local = h4.x + h4.y + h4.z + h4.w;
        int s = local;
#pragma unroll
        for (int o = 1; o < 64; o <<= 1) {
            int x = __shfl_down(s, o);
            if (tid + o < 64) s += x;
        }
        int sufE = s - local;
        Sarr[tid * 4 + 0] = sufE + h4.y + h4.z + h4.w;
        Sarr[tid * 4 + 1] = sufE + h4.z + h4.w;
        Sarr[tid * 4 + 2] = sufE + h4.w;
        Sarr[tid * 4 + 3] = sufE;
    }
    __syncthreads();
    if (Sarr[tid] < TOPK_ && Sarr[tid] + hist[tid] >= TOPK_) bsel1 = tid;
    __syncthreads();
    const int b1 = bsel1;
    const int S1 = Sarr[b1];
    for (int k = tid; k < SPLIT; k += 256) {
        unsigned mono = keyhi[k];
        if ((int)(mono >> 24) == b1) atomicAdd(&hist2[(mono >> 16) & 255], 1);
    }
    __syncthreads();
    if (tid < 64) {
        int4 h4 = *(const int4*)&hist2[tid * 4];
        int local = h4.x + h4.y + h4.z + h4.w;
        int s = local;
#pragma unroll
        for (int o = 1; o < 64; o <<= 1) {
            int x = __shfl_down(s, o);
            if (tid + o < 64) s += x;
        }
        int sufE = s - local;
        Sarr[tid * 4 + 0] = sufE + h4.y + h4.z + h4.w;
        Sarr[tid * 4 + 1] = sufE + h4.z + h4.w;
        Sarr[tid * 4 + 2] = sufE + h4.w;
        Sarr[tid * 4 + 3] = sufE;
    }
    __syncthreads();
    if (S1 + Sarr[tid] < TOPK_ && S1 + Sarr[tid] + hist2[tid] >= TOPK_) bsel2 = tid;
    __syncthreads();
    const int b2 = bsel2;
    for (int k = tid; k < SPLIT; k += 256) {
        unsigned mono = keyhi[k];
        int hi = mono >> 24, mid = (mono >> 16) & 255;
        if (hi > b1 || (hi == b1 && mid >= b2)) {
            int s = atomicAdd(&ccnt, 1);
            cand[s] = ((unsigned long long)mono << 10) | (unsigned)(1023 - k);
        }
    }
    __syncthreads();
    const int n = ccnt;
    for (int ci = tid; ci < n; ci += 256) {
        unsigned long long mine = cand[ci];
        int r = 0;
        for (int j = 0; j < n; j++) r += (cand[j] > mine);
        if (r < TOPK_)
            idx_out[(size_t)bid * TOPK_ + r] = 1023 - (int)(mine & 1023ull);
    }
}

// ---------------------------------------------------------------------------
// MLA absorption part 1 -> bf16: G16[q][h*128+l] = sum_d qb[q][h*32+d]*uw[h*32+d][l]
// ---------------------------------------------------------------------------
__global__ __launch_bounds__(256) void mla_g(const float* __restrict__ qb,
                                             const float* __restrict__ uw,
                                             unsigned short* __restrict__ G16)
{
    int qt = blockIdx.x, h = blockIdx.y, tid = threadIdx.x;
    __shared__ float Qs[64][33];
    __shared__ float Us[32][132];
    {
        int r = tid >> 2, c0 = (tid & 3) * 8;
        const float* srcp = qb + ((size_t)(qt * 64 + r)) * E_ + h * DH + c0;
        float4 a = ((const float4*)srcp)[0];
        float4 b = ((const float4*)srcp)[1];
        Qs[r][c0 + 0] = a.x; Qs[r][c0 + 1] = a.y; Qs[r][c0 + 2] = a.z; Qs[r][c0 + 3] = a.w;
        Qs[r][c0 + 4] = b.x; Qs[r][c0 + 5] = b.y; Qs[r][c0 + 6] = b.z; Qs[r][c0 + 7] = b.w;
    }
    {
        int d = tid >> 3, l0 = (tid & 7) * 16;
        const float* srcp = uw + (size_t)(h * DH + d) * LATD + l0;
#pragma unroll
        for (int ii = 0; ii < 4; ii++) {
            float4 v = ((const float4*)srcp)[ii];
            *(float4*)&Us[d][l0 + ii * 4] = v;
        }
    }
    __syncthreads();
    int rg = tid >> 5, l = (tid & 31) * 4;
    float acc[8][4];
#pragma unroll
    for (int i = 0; i < 8; i++)
#pragma unroll
        for (int j = 0; j < 4; j++) acc[i][j] = 0.f;
    for (int d = 0; d < DH; d++) {
        float4 u = *(const float4*)&Us[d][l];
#pragma unroll
        for (int i = 0; i < 8; i++) {
            float qv = Qs[rg * 8 + i][d];
            acc[i][0] += qv * u.x; acc[i][1] += qv * u.y;
            acc[i][2] += qv * u.z; acc[i][3] += qv * u.w;
        }
    }
#pragma unroll
    for (int i = 0; i < 8; i++) {
        ushort4 o;
        o.x = f2b(acc[i][0]); o.y = f2b(acc[i][1]);
        o.z = f2b(acc[i][2]); o.w = f2b(acc[i][3]);
        *(ushort4*)(G16 + ((size_t)(qt * 64 + rg * 8 + i)) * 1024 + h * 128 + l) = o;
    }
}

// ---------------------------------------------------------------------------
// Fused sparse MLA attention: ONE WAVE per query, MFMA-based, barrier-free.
// Scores: S^T = G (8x128) @ C_sel^T  via 2 j-tiles x 4 K-chunks of 16x16x32;
//   A-frags & B-frags read DIRECTLY from global (G16, cb16) - L2 resident.
// Softmax in-wave (shfl over 16-lane groups).
// PV: M = W^T (8x32) @ C (32x128) via 8 col-tiles of 16x16x32;
//   B-frags from LDS C^T (scalar-transposed at staging), A from LDS wT.
// ---------------------------------------------------------------------------
__global__ __launch_bounds__(64) void mla_attn(const unsigned short* __restrict__ G16,
                                               const unsigned short* __restrict__ cb16,
                                               const int* __restrict__ idxb,
                                               unsigned short* __restrict__ Mo16)
{
    const int bid = blockIdx.x, l = threadIdx.x;
    const int bf = bid >> 10;
    __shared__ __align__(16) unsigned short ct[128][40];  // C^T [l-dim][j+pad]
    __shared__ __align__(16) unsigned short wT[16][40];   // w^T [h(16)][j+pad]
    __shared__ int sidx[32];
    if (l < 32) sidx[l] = idxb[(size_t)bid * 32 + l];

    const int n16 = l & 15, g = l >> 4;

    // ---- stage C^T (transpose write) ----
    {
        int j = l >> 1, c0 = (l & 1) * 64;
        const unsigned short* crow = cb16 + ((size_t)(bf * SPLIT + sidx[j])) * 128 + c0;
#pragma unroll
        for (int e = 0; e < 8; e++) {
            uint4 v = *(const uint4*)(crow + e * 8);
            unsigned short tmp[8];
            *(uint4*)tmp = v;
#pragma unroll
            for (int t = 0; t < 8; t++) ct[c0 + e * 8 + t][j] = tmp[t];
        }
    }

    // ---- scores: S^T = G @ C^T (global-direct fragments) ----
    // A-frag: row = lane&15 (rows 8-15 duplicate rows 0-7 -> clean dups)
    const unsigned short* Ab = G16 + (size_t)bid * 1024 + (size_t)(l & 7) * 128 + g * 8;
    const int j0 = sidx[n16], j1 = sidx[16 + n16];
    const unsigned short* B0 = cb16 + ((size_t)(bf * SPLIT + j0)) * 128 + g * 8;
    const unsigned short* B1 = cb16 + ((size_t)(bf * SPLIT + j1)) * 128 + g * 8;
    f32x4v s0 = {0.f, 0.f, 0.f, 0.f}, s1 = {0.f, 0.f, 0.f, 0.f};
#pragma unroll
    for (int c = 0; c < 4; c++) {
        bf16x8 a  = *(const bf16x8*)(Ab + c * 32);
        bf16x8 b0 = *(const bf16x8*)(B0 + c * 32);
        bf16x8 b1 = *(const bf16x8*)(B1 + c * 32);
        s0 = __builtin_amdgcn_mfma_f32_16x16x32_bf16(a, b0, s0, 0, 0, 0);
        s1 = __builtin_amdgcn_mfma_f32_16x16x32_bf16(a, b1, s1, 0, 0, 0);
    }

    // ---- softmax over j (32 vals: 16 lanes x 2 regs), per h-row ----
    const float scale = 0.17677669529663688f;
#pragma unroll
    for (int r = 0; r < 4; r++) {
        float a0 = s0[r] * scale, a1 = s1[r] * scale;
        float mx = fmaxf(a0, a1);
#pragma unroll
        for (int o = 1; o < 16; o <<= 1) mx = fmaxf(mx, __shfl_xor(mx, o));
        float e0 = expf(a0 - mx), e1 = expf(a1 - mx);
        float sm = e0 + e1;
#pragma unroll
        for (int o = 1; o < 16; o <<= 1) sm += __shfl_xor(sm, o);
        float inv = 1.0f / sm;
        wT[g * 4 + r][n16]      = f2b(e0 * inv);
        wT[g * 4 + r][16 + n16] = f2b(e1 * inv);
    }

    // ---- PV: M = W^T @ C ----
    bf16x8 aw = *(const bf16x8*)&wT[n16][g * 8];
#pragma unroll
    for (int t = 0; t < 8; t++) {
        bf16x8 bc = *(const bf16x8*)&ct[t * 16 + n16][g * 8];
        f32x4v m = {0.f, 0.f, 0.f, 0.f};
        m = __builtin_amdgcn_mfma_f32_16x16x32_bf16(aw, bc, m, 0, 0, 0);
        if (g < 2) {
#pragma unroll
            for (int r = 0; r < 4; r++)
                Mo16[(size_t)bid * 1024 + (size_t)(g * 4 + r) * 128 + t * 16 + n16] = f2b(m[r]);
        }
    }
}

// ---------------------------------------------------------------------------
// MLA absorption part 2 (reads bf16 M) -> bf16 output
// ---------------------------------------------------------------------------
__global__ __launch_bounds__(256) void mla_out(const unsigned short* __restrict__ Mo16,
                                               const float* __restrict__ uw,
                                               unsigned short* __restrict__ ob)
{
    int qt = blockIdx.x, h = blockIdx.y, tid = threadIdx.x;
    __shared__ float Ms[64][132];
    __shared__ float Us[32][129];
    {
        int r = tid >> 2, l0 = (tid & 3) * 32;
        const unsigned short* srcp = Mo16 + ((size_t)(qt * 64 + r)) * 1024 + h * 128 + l0;
#pragma unroll
        for (int ii = 0; ii < 4; ii++) {
            uint4 v = ((const uint4*)srcp)[ii];
            unsigned short u[8];
            *(uint4*)u = v;
#pragma unroll
            for (int t = 0; t < 8; t++) Ms[r][l0 + ii * 8 + t] = b2f(u[t]);
        }
    }
    {
        int d = tid >> 3, l0 = (tid & 7) * 16;
        const float* srcp = uw + (size_t)(256 + h * DH + d) * LATD + l0;
#pragma unroll
        for (int ii = 0; ii < 4; ii++) {
            float4 v = ((const float4*)srcp)[ii];
            Us[d][l0 + ii * 4 + 0] = v.x; Us[d][l0 + ii * 4 + 1] = v.y;
            Us[d][l0 + ii * 4 + 2] = v.z; Us[d][l0 + ii * 4 + 3] = v.w;
        }
    }
    __syncthreads();
    int d = tid & 31, rg = tid >> 5;
    float acc[8] = {0, 0, 0, 0, 0, 0, 0, 0};
    for (int ll = 0; ll < 128; ll++) {
        float u = Us[d][ll];
#pragma unroll
        for (int i = 0; i < 8; i++) acc[i] += Ms[rg * 8 + i][ll] * u;
    }
#pragma unroll
    for (int i = 0; i < 8; i++)
        ob[((size_t)(qt * 64 + rg * 8 + i)) * E_ + h * DH + d] = f2b(acc[i]);
}

// ---------------------------------------------------------------------------
extern "C" void kernel_launch(void* const* d_in, const int* in_sizes, int n_in,
                              void* d_out, int out_size, void* d_ws, size_t ws_size,
                              hipStream_t stream)
{
    (void)in_sizes; (void)n_in; (void)out_size; (void)ws_size;
    const float* src      = (const float*)d_in[0];
    const float* fa_in_w  = (const float*)d_in[2];
    const float* fa_in_b  = (const float*)d_in[3];
    const float* fa_out_w = (const float*)d_in[4];
    const float* fa_out_b = (const float*)d_in[5];
    const float* n1g = (const float*)d_in[6];
    const float* n1b = (const float*)d_in[7];
    const float* iqw = (const float*)d_in[8];
    const float* ikw = (const float*)d_in[9];
    const float* iow = (const float*)d_in[10];
    const float* mqw = (const float*)d_in[11];
    const float* mdw = (const float*)d_in[12];
    const float* muw = (const float*)d_in[13];
    const float* mow = (const float*)d_in[14];
    const float* n2g = (const float*)d_in[15];
    const float* n2b = (const float*)d_in[16];
    const float* l1w = (const float*)d_in[17];
    const float* l1b = (const float*)d_in[18];
    const float* l2w = (const float*)d_in[19];
    const float* l2b = (const float*)d_in[20];
    const float* n3g = (const float*)d_in[21];
    const float* n3b = (const float*)d_in[22];

    float* ws = (float*)d_ws;
    size_t off = 0;
    auto alloc = [&](size_t n) { float* p = ws + off; off += (n + 3) & ~(size_t)3; return p; };

    float* bigA = alloc((size_t)NT * 1024);   // qkv -> G16 -> x2
    float* Mh   = alloc((size_t)NT * 1024);   // Mo16; later h1 bf16
    float* tbuf = alloc((size_t)NT * E_);     // pre-LN buf; doubles as qb
    float* stb  = alloc((size_t)NT * E_);     // st f32 (post-LN1, transposed)
    float* cbws = alloc((size_t)BF * SPLIT * LATD / 2 + 16);   // cb16 bf16
    unsigned short* actBF1 = (unsigned short*)alloc((size_t)NT * E_ / 2);
    unsigned short* actBF2 = (unsigned short*)alloc((size_t)NT * E_ / 2);
    float* qk32 = alloc((size_t)NT * 64);
    float* scl = alloc(128);
    int*   idxb = (int*)alloc((size_t)NT * 32);
    signed char* ki8 = (signed char*)alloc((size_t)NT * 32 / 4);
    unsigned short* w16 = (unsigned short*)alloc(950272 / 2 + 8);
    unsigned short* wqk16 = (unsigned short*)alloc(16384 / 2 + 8);

    unsigned short* fa_in_w16  = w16;
    unsigned short* fa_out_w16 = fa_in_w16 + 196608;
    unsigned short* mqw16      = fa_out_w16 + 65536;
    unsigned short* mdw16      = mqw16 + 65536;
    unsigned short* mow16      = mdw16 + 32768;
    unsigned short* l1w16      = mow16 + 65536;
    unsigned short* l2w16      = l1w16 + 262144;

    float* qkv = bigA;
    unsigned short* G16 = (unsigned short*)bigA;
    float* x2  = bigA;
    unsigned short* Mo16 = (unsigned short*)Mh;
    unsigned short* h116 = (unsigned short*)Mh;
    float* qb = tbuf;
    unsigned short* cb16 = (unsigned short*)cbws;
    unsigned short* src16  = actBF1;
    unsigned short* abuf16 = actBF1;
    unsigned short* stb16  = actBF1;
    unsigned short* ob16   = actBF2;
    unsigned short* x216   = actBF2;

    // 0. convert weights + src to bf16
    ConvArgs ca;
    const float* segs[10] = {src, fa_in_w, fa_out_w, mqw, mdw, mow, l1w, l2w, iqw, ikw};
    unsigned short* segd[10] = {src16, fa_in_w16, fa_out_w16, mqw16, mdw16, mow16, l1w16, l2w16,
                                wqk16, wqk16 + 8192};
    int segn[10] = {NT * E_, 196608, 65536, 65536, 32768, 65536, 262144, 262144, 8192, 8192};
    int cum = 0;
    for (int i = 0; i < 10; i++) { ca.s[i] = segs[i]; ca.d[i] = segd[i]; cum += segn[i] / 4; ca.cum[i] = cum; }
    int totq = cum;
    convert_f2b<<<(totq + 255) / 256, 256, 0, stream>>>(ca, totq);

    dim3 blk(256);
    // 1. qkv = src @ fa_in_w^T + b
    gemm_mfma<128,128,1,0,0,0,0,0><<<dim3(6,64), blk, 0, stream>>>(src16, fa_in_w16, fa_in_b, nullptr, qkv, nullptr, NT, 768, 256);
    // 2. feature attention (S=4) -> bf16
    fa_attn<<<2048, blk, 0, stream>>>(qkv, abuf16);
    // 3. out-proj + bias + residual(src)
    gemm_mfma<128,64,1,0,1,0,0,0><<<dim3(4,64), blk, 0, stream>>>(abuf16, fa_out_w16, fa_out_b, src, tbuf, nullptr, NT, 256, 256);
    // 4. LN1, write transposed f32 + bf16
    ln_k<1,1><<<NT/4, blk, 0, stream>>>(tbuf, n1g, n1b, stb, stb16);
    // 5. indexer projections as MFMA GEMM -> qk32 [row][64]
    gemm_mfma<128,64,0,0,0,0,0,0><<<dim3(1,64), blk, 0, stream>>>(stb16, wqk16, nullptr, nullptr, qk32, nullptr, NT, 64, 256);
    // 6. scales
    idx_scales<<<96, blk, 0, stream>>>(qk32, scl);
    // 7. quantize k
    idx_quantk<<<(BF * SPLIT * 32) / 256, blk, 0, stream>>>(qk32, scl, ki8);
    // 8. scores + top-32 (radix-select)
    idx_score_topk<<<NT, blk, 0, stream>>>(qk32, ki8, scl, iow, idxb);
    // 9. c = x_tr @ down_w^T  -> bf16 cb16
    gemm_mfma<64,64,0,0,0,1,0,1><<<dim3(2,96), blk, 0, stream>>>(stb16, mdw16, nullptr, nullptr, nullptr, cb16, BF * SPLIT, 128, 256);
    // 10. mla q projection
    gemm_mfma<128,64,0,0,0,0,0,0><<<dim3(4,64), blk, 0, stream>>>(stb16, mqw16, nullptr, nullptr, qb, nullptr, NT, 256, 256);
    // 11. G16 = per-head up_w(K-half)^T @ q  (bf16)
    mla_g<<<dim3(128,8), blk, 0, stream>>>(qb, muw, G16);
    // 12. fused sparse attention (1 wave/query, MFMA) -> Mo16
    mla_attn<<<NT, dim3(64), 0, stream>>>(G16, cb16, idxb, Mo16);
    // 13. out = per-head up_w(V-half) @ M -> bf16
    mla_out<<<dim3(128,8), blk, 0, stream>>>(Mo16, muw, ob16);
    // 14. mla out-proj + residual(stb), scatter to BRCE token rows
    gemm_mfma<128,64,0,0,1,0,1,0><<<dim3(4,64), blk, 0, stream>>>(ob16, mow16, nullptr, stb, tbuf, nullptr, NT, 256, 256);
    // 15. LN2 -> x2 f32 + bf16
    ln_k<0,1><<<NT/4, blk, 0, stream>>>(tbuf, n2g, n2b, x2, x216);
    // 16. MLP1 + GELU -> bf16 h1
    gemm_mfma<128,128,1,1,0,0,0,1><<<dim3(8,64), blk, 0, stream>>>(x216, l1w16, l1b, nullptr, nullptr, h116, NT, MLPD, 256);
    // 17. MLP2 + bias + residual(x2)
    gemm_mfma<128,64,1,0,1,0,0,0><<<dim3(4,64), blk, 0, stream>>>(h116, l2w16, l2b, x2, tbuf, nullptr, NT, 256, MLPD);
    // 18. LN3 -> output
    ln_k<0,0><<<NT/4, blk, 0, stream>>>(tbuf, n3g, n3b, (float*)d_out, nullptr);
}